// Round 9
// baseline (685.494 us; speedup 1.0000x reference)
//
#include <hip/hip_runtime.h>
#include <hip/hip_bf16.h>

#define N_NODES 100000
#define N_EDGES 1600000
#define FEAT 64
#define NGRAPH 256

#define SCAN_CHUNK 1024
#define SCAN_BLOCKS ((N_NODES + SCAN_CHUNK - 1) / SCAN_CHUNK)  // 98

// coarse buckets: 1024 nodes each
#define CB_SHIFT 10
#define CB_NODES 1024
#define NCB ((N_NODES + CB_NODES - 1) / CB_NODES)   // 98
#define CB_CAP 18432                                 // slots per bucket

#define PB 512                                       // partition blocks
#define EPB ((N_EDGES + PB - 1) / PB)                // 3125 edges per block

typedef unsigned short u16;
typedef unsigned int u32;

static __device__ __forceinline__ float bf2f(u16 h) {
    return __uint_as_float(((u32)h) << 16);
}
static __device__ __forceinline__ u16 f2bf(float x) {  // round-to-nearest-even (finite)
    u32 u = __float_as_uint(x);
    return (u16)((u + 0x7FFF + ((u >> 16) & 1)) >> 16);
}
static __device__ __forceinline__ float2 up2(u32 v) {
    return make_float2(bf2f((u16)(v & 0xFFFF)), bf2f((u16)(v >> 16)));
}

// ---------------- two-pass multisplit partition into coarse buckets ----------------

__global__ __launch_bounds__(256) void k_phist(const int* __restrict__ dst,
                                               int* __restrict__ bhist) {
    __shared__ int cnt[NCB];
    int t = threadIdx.x;
    for (int i = t; i < NCB; i += 256) cnt[i] = 0;
    __syncthreads();
    int begin = blockIdx.x * EPB;
    int end = begin + EPB; if (end > N_EDGES) end = N_EDGES;
    for (int e = begin + t; e < end; e += 256)
        atomicAdd(&cnt[dst[e] >> CB_SHIFT], 1);
    __syncthreads();
    for (int i = t; i < NCB; i += 256) bhist[i * PB + blockIdx.x] = cnt[i];
}

__global__ __launch_bounds__(PB) void k_pscan(int* __restrict__ bhist,
                                              int* __restrict__ gtot) {
    __shared__ int s[PB];
    int b = blockIdx.x, t = threadIdx.x;
    int v = bhist[b * PB + t];
    s[t] = v;
    __syncthreads();
    for (int off = 1; off < PB; off <<= 1) {
        int add = (t >= off) ? s[t - off] : 0;
        __syncthreads();
        s[t] += add;
        __syncthreads();
    }
    int incl = s[t];
    bhist[b * PB + t] = (t ? s[t - 1] : 0);
    if (t == PB - 1) gtot[b] = incl;
}

__global__ __launch_bounds__(256) void k_pscatter(const int* __restrict__ src,
                                                  const int* __restrict__ dst,
                                                  const int* __restrict__ bhist,
                                                  int* __restrict__ tmp) {
    __shared__ int cur[NCB];
    int t = threadIdx.x;
    for (int i = t; i < NCB; i += 256) cur[i] = bhist[i * PB + blockIdx.x];
    __syncthreads();
    int begin = blockIdx.x * EPB;
    int end = begin + EPB; if (end > N_EDGES) end = N_EDGES;
    for (int e = begin + t; e < end; e += 256) {
        int d = dst[e];
        int b = d >> CB_SHIFT;
        int pos = atomicAdd(&cur[b], 1);
        if (pos < CB_CAP) tmp[b * CB_CAP + pos] = ((d & (CB_NODES - 1)) << 17) | src[e];
    }
}

// ---------------- per-bucket degree count ----------------

__global__ __launch_bounds__(256) void k_bdeg(const int* __restrict__ tmp,
                                              const int* __restrict__ gtot,
                                              int* __restrict__ deg) {
    __shared__ int cnt[CB_NODES];
    int b = blockIdx.x, t = threadIdx.x;
    for (int j = t; j < CB_NODES; j += 256) cnt[j] = 0;
    __syncthreads();
    int n = gtot[b]; if (n > CB_CAP) n = CB_CAP;
    const int* tp = &tmp[b * CB_CAP];
    for (int i = t; i < n; i += 256) atomicAdd(&cnt[tp[i] >> 17], 1);
    __syncthreads();
    int n0 = b << CB_SHIFT;
    for (int j = t; j < CB_NODES; j += 256) {
        int node = n0 + j;
        if (node < N_NODES) deg[node] = cnt[j];
    }
}

// ---------------- CSR offset scan ----------------

__global__ __launch_bounds__(256) void k_scan1(const int* __restrict__ deg,
                                               int* __restrict__ bsum) {
    int t = threadIdx.x;
    int base = blockIdx.x * SCAN_CHUNK + t * 4;
    int4 d = make_int4(0, 0, 0, 0);
    if (base + 3 < N_NODES) {
        d = *reinterpret_cast<const int4*>(&deg[base]);
    } else {
        if (base + 0 < N_NODES) d.x = deg[base + 0];
        if (base + 1 < N_NODES) d.y = deg[base + 1];
        if (base + 2 < N_NODES) d.z = deg[base + 2];
    }
    int v = d.x + d.y + d.z + d.w;
#pragma unroll
    for (int off = 32; off; off >>= 1) v += __shfl_xor(v, off);
    __shared__ int red[4];
    int lane = t & 63, wid = t >> 6;
    if (lane == 0) red[wid] = v;
    __syncthreads();
    if (t == 0) bsum[blockIdx.x] = red[0] + red[1] + red[2] + red[3];
}

__global__ __launch_bounds__(128) void k_scan2(int* __restrict__ bsum) {
    __shared__ int s[128];
    int t = threadIdx.x;
    int v = (t < SCAN_BLOCKS) ? bsum[t] : 0;
    s[t] = v;
    __syncthreads();
    for (int off = 1; off < 128; off <<= 1) {
        int add = (t >= off) ? s[t - off] : 0;
        __syncthreads();
        s[t] += add;
        __syncthreads();
    }
    if (t < SCAN_BLOCKS) bsum[t] = (t ? s[t - 1] : 0);
}

__global__ __launch_bounds__(256) void k_scan3(int* __restrict__ deg_off,
                                               const int* __restrict__ bsum) {
    int t = threadIdx.x;
    int base = blockIdx.x * SCAN_CHUNK + t * 4;
    int4 d = make_int4(0, 0, 0, 0);
    bool full = (base + 3 < N_NODES);
    if (full) {
        d = *reinterpret_cast<const int4*>(&deg_off[base]);
    } else {
        if (base + 0 < N_NODES) d.x = deg_off[base + 0];
        if (base + 1 < N_NODES) d.y = deg_off[base + 1];
        if (base + 2 < N_NODES) d.z = deg_off[base + 2];
    }
    int total = d.x + d.y + d.z + d.w;
    __shared__ int sc[256];
    sc[t] = total;
    __syncthreads();
    for (int off = 1; off < 256; off <<= 1) {
        int add = (t >= off) ? sc[t - off] : 0;
        __syncthreads();
        sc[t] += add;
        __syncthreads();
    }
    int texc = (t ? sc[t - 1] : 0) + bsum[blockIdx.x];
    int4 o;
    o.x = texc;
    o.y = o.x + d.x;
    o.z = o.y + d.y;
    o.w = o.z + d.z;
    if (full) {
        *reinterpret_cast<int4*>(&deg_off[base]) = o;
    } else {
        if (base + 0 < N_NODES) deg_off[base + 0] = o.x;
        if (base + 1 < N_NODES) deg_off[base + 1] = o.y;
        if (base + 2 < N_NODES) deg_off[base + 2] = o.z;
    }
}

// ---------------- per-bucket scatter into CSR order ----------------

__global__ __launch_bounds__(256) void k_bsort(const int* __restrict__ tmp,
                                               const int* __restrict__ offs,
                                               const int* __restrict__ gtot,
                                               int* __restrict__ ssrc) {
    __shared__ int lcur[CB_NODES];
    int b = blockIdx.x;
    int n0 = b << CB_SHIFT;
    int t = threadIdx.x;
    for (int j = t; j < CB_NODES; j += 256) {
        int n = n0 + j;
        lcur[j] = (n < N_NODES) ? offs[n] : 0;
    }
    __syncthreads();
    int cnt = gtot[b]; if (cnt > CB_CAP) cnt = CB_CAP;
    const int* tp = &tmp[b * CB_CAP];
    for (int i = t; i < cnt; i += 256) {
        int p = tp[i];
        int pos = atomicAdd(&lcur[p >> 17], 1);
        ssrc[pos] = p & 0x1FFFF;
    }
}

// ---------------- x (f32) -> bf16 node table ----------------

__global__ __launch_bounds__(256) void k_cvt(const float* __restrict__ x,
                                             u16* __restrict__ hb) {
    int i = blockIdx.x * 256 + threadIdx.x;  // 8 elems each
    const int total = N_NODES * FEAT / 8;
    if (i < total) {
        const float4* xv = (const float4*)x;
        float4 a = xv[2 * i], b = xv[2 * i + 1];
        uint4 o;
        o.x = f2bf(a.x) | ((u32)f2bf(a.y) << 16);
        o.y = f2bf(a.z) | ((u32)f2bf(a.w) << 16);
        o.z = f2bf(b.x) | ((u32)f2bf(b.y) << 16);
        o.w = f2bf(b.z) | ((u32)f2bf(b.w) << 16);
        ((uint4*)hb)[i] = o;
    }
}

// ---------------- GIN aggregation: 2 nodes/wave, unroll-8 gather pipeline ----------------
// agg output is bf16-packed (u32 of 2 feats per lane).

__global__ __launch_bounds__(256) void k_aggregate(const u16* __restrict__ hb,
                                                   u32* __restrict__ aggb,
                                                   const int* __restrict__ offs,
                                                   const int* __restrict__ ssrc) {
    int w = threadIdx.x >> 6;
    int lane = threadIdx.x & 63;
    int half = lane >> 5;
    int li = lane & 31;
    int node = blockIdx.x * 8 + w * 2 + half;
    if (node >= N_NODES) return;
    const u32* hb32 = (const u32*)hb;
    float2 p = up2(hb32[node * 32 + li]);
    float v0 = p.x, v1 = p.y;
    int s = offs[node];
    int e = (node + 1 < N_NODES) ? offs[node + 1] : N_EDGES;
    int j = s;
    for (; j + 7 < e; j += 8) {
        int s0 = ssrc[j], s1 = ssrc[j + 1], s2 = ssrc[j + 2], s3 = ssrc[j + 3];
        int s4 = ssrc[j + 4], s5 = ssrc[j + 5], s6 = ssrc[j + 6], s7 = ssrc[j + 7];
        u32 n0 = hb32[s0 * 32 + li];
        u32 n1 = hb32[s1 * 32 + li];
        u32 n2 = hb32[s2 * 32 + li];
        u32 n3 = hb32[s3 * 32 + li];
        u32 n4 = hb32[s4 * 32 + li];
        u32 n5 = hb32[s5 * 32 + li];
        u32 n6 = hb32[s6 * 32 + li];
        u32 n7 = hb32[s7 * 32 + li];
        float2 a0 = up2(n0), a1 = up2(n1), a2 = up2(n2), a3 = up2(n3);
        float2 a4 = up2(n4), a5 = up2(n5), a6 = up2(n6), a7 = up2(n7);
        v0 += a0.x + a1.x + a2.x + a3.x + a4.x + a5.x + a6.x + a7.x;
        v1 += a0.y + a1.y + a2.y + a3.y + a4.y + a5.y + a6.y + a7.y;
    }
    if (j + 3 < e) {
        int s0 = ssrc[j], s1 = ssrc[j + 1], s2 = ssrc[j + 2], s3 = ssrc[j + 3];
        u32 n0 = hb32[s0 * 32 + li];
        u32 n1 = hb32[s1 * 32 + li];
        u32 n2 = hb32[s2 * 32 + li];
        u32 n3 = hb32[s3 * 32 + li];
        float2 a0 = up2(n0), a1 = up2(n1), a2 = up2(n2), a3 = up2(n3);
        v0 += a0.x + a1.x + a2.x + a3.x;
        v1 += a0.y + a1.y + a2.y + a3.y;
        j += 4;
    }
    for (; j < e; ++j) {
        float2 a = up2(hb32[ssrc[j] * 32 + li]);
        v0 += a.x; v1 += a.y;
    }
    aggb[node * 32 + li] = f2bf(v0) | ((u32)f2bf(v1) << 16);
}

// ---------------- fused 64->64->64 MLP (bf16 in, f32 math, bf16 out) ----------------

template <bool RELU_OUT>
__global__ __launch_bounds__(256) void k_mlp(const u32* __restrict__ aggb,
                                             u16* __restrict__ hout,
                                             const float* __restrict__ W1,
                                             const float* __restrict__ b1,
                                             const float* __restrict__ W2,
                                             const float* __restrict__ b2) {
    __shared__ float w1s[FEAT * FEAT];
    __shared__ float w2s[FEAT * FEAT];
    __shared__ float b1s[FEAT];
    __shared__ float b2s[FEAT];
    {
        const float4* W1v = (const float4*)W1;
        const float4* W2v = (const float4*)W2;
        float4* w1sv = (float4*)w1s;
        float4* w2sv = (float4*)w2s;
        for (int i = threadIdx.x; i < FEAT * FEAT / 4; i += 256) {
            w1sv[i] = W1v[i];
            w2sv[i] = W2v[i];
        }
        if (threadIdx.x < FEAT) {
            b1s[threadIdx.x] = b1[threadIdx.x];
            b2s[threadIdx.x] = b2[threadIdx.x];
        }
    }
    __syncthreads();

    int node = blockIdx.x * 256 + threadIdx.x;
    if (node >= N_NODES) return;

    float a[FEAT], h[FEAT];
    const uint4* av = (const uint4*)(aggb + (size_t)node * 32);
#pragma unroll
    for (int q = 0; q < 8; ++q) {
        uint4 v = av[q];
        float2 e0 = up2(v.x), e1 = up2(v.y), e2 = up2(v.z), e3 = up2(v.w);
        a[8 * q + 0] = e0.x; a[8 * q + 1] = e0.y;
        a[8 * q + 2] = e1.x; a[8 * q + 3] = e1.y;
        a[8 * q + 4] = e2.x; a[8 * q + 5] = e2.y;
        a[8 * q + 6] = e3.x; a[8 * q + 7] = e3.y;
    }

    const float4* w1v = (const float4*)w1s;
    const float4* b1v = (const float4*)b1s;
#pragma unroll
    for (int q = 0; q < FEAT / 4; ++q) {
        float4 b = b1v[q];
        h[4 * q + 0] = b.x; h[4 * q + 1] = b.y; h[4 * q + 2] = b.z; h[4 * q + 3] = b.w;
    }
#pragma unroll
    for (int k = 0; k < FEAT; ++k) {
        float ak = a[k];
#pragma unroll
        for (int q = 0; q < FEAT / 4; ++q) {
            float4 w = w1v[k * (FEAT / 4) + q];
            h[4 * q + 0] = fmaf(ak, w.x, h[4 * q + 0]);
            h[4 * q + 1] = fmaf(ak, w.y, h[4 * q + 1]);
            h[4 * q + 2] = fmaf(ak, w.z, h[4 * q + 2]);
            h[4 * q + 3] = fmaf(ak, w.w, h[4 * q + 3]);
        }
    }
#pragma unroll
    for (int j = 0; j < FEAT; ++j) h[j] = fmaxf(h[j], 0.0f);

    const float4* w2v = (const float4*)w2s;
    const float4* b2v = (const float4*)b2s;
#pragma unroll
    for (int q = 0; q < FEAT / 4; ++q) {
        float4 b = b2v[q];
        a[4 * q + 0] = b.x; a[4 * q + 1] = b.y; a[4 * q + 2] = b.z; a[4 * q + 3] = b.w;
    }
#pragma unroll
    for (int k = 0; k < FEAT; ++k) {
        float hk = h[k];
#pragma unroll
        for (int q = 0; q < FEAT / 4; ++q) {
            float4 w = w2v[k * (FEAT / 4) + q];
            a[4 * q + 0] = fmaf(hk, w.x, a[4 * q + 0]);
            a[4 * q + 1] = fmaf(hk, w.y, a[4 * q + 1]);
            a[4 * q + 2] = fmaf(hk, w.z, a[4 * q + 2]);
            a[4 * q + 3] = fmaf(hk, w.w, a[4 * q + 3]);
        }
    }
    if (RELU_OUT) {
#pragma unroll
        for (int j = 0; j < FEAT; ++j) a[j] = fmaxf(a[j], 0.0f);
    }

    u32 w[FEAT / 2];
#pragma unroll
    for (int q = 0; q < FEAT / 2; ++q)
        w[q] = f2bf(a[2 * q]) | ((u32)f2bf(a[2 * q + 1]) << 16);
    uint4* ov = (uint4*)(hout + (size_t)node * FEAT);
#pragma unroll
    for (int q = 0; q < FEAT / 8; ++q)
        ov[q] = make_uint4(w[4 * q + 0], w[4 * q + 1], w[4 * q + 2], w[4 * q + 3]);
}

// ---------------- last layer: fused aggregate + (64->1->1), unroll-8 ----------------

__global__ __launch_bounds__(256) void k_lastagg(const u16* __restrict__ hb,
                                                 const int* __restrict__ offs,
                                                 const int* __restrict__ ssrc,
                                                 const float* __restrict__ W1l,
                                                 const float* __restrict__ b1l,
                                                 const float* __restrict__ W2l,
                                                 const float* __restrict__ b2l,
                                                 float* __restrict__ o) {
    int w = threadIdx.x >> 6;
    int lane = threadIdx.x & 63;
    int half = lane >> 5;
    int li = lane & 31;
    int node = blockIdx.x * 8 + w * 2 + half;
    if (node >= N_NODES) return;
    const u32* hb32 = (const u32*)hb;
    float2 p = up2(hb32[node * 32 + li]);
    float v0 = p.x, v1 = p.y;
    int s = offs[node];
    int e = (node + 1 < N_NODES) ? offs[node + 1] : N_EDGES;
    int j = s;
    for (; j + 7 < e; j += 8) {
        int s0 = ssrc[j], s1 = ssrc[j + 1], s2 = ssrc[j + 2], s3 = ssrc[j + 3];
        int s4 = ssrc[j + 4], s5 = ssrc[j + 5], s6 = ssrc[j + 6], s7 = ssrc[j + 7];
        u32 n0 = hb32[s0 * 32 + li];
        u32 n1 = hb32[s1 * 32 + li];
        u32 n2 = hb32[s2 * 32 + li];
        u32 n3 = hb32[s3 * 32 + li];
        u32 n4 = hb32[s4 * 32 + li];
        u32 n5 = hb32[s5 * 32 + li];
        u32 n6 = hb32[s6 * 32 + li];
        u32 n7 = hb32[s7 * 32 + li];
        float2 a0 = up2(n0), a1 = up2(n1), a2 = up2(n2), a3 = up2(n3);
        float2 a4 = up2(n4), a5 = up2(n5), a6 = up2(n6), a7 = up2(n7);
        v0 += a0.x + a1.x + a2.x + a3.x + a4.x + a5.x + a6.x + a7.x;
        v1 += a0.y + a1.y + a2.y + a3.y + a4.y + a5.y + a6.y + a7.y;
    }
    if (j + 3 < e) {
        int s0 = ssrc[j], s1 = ssrc[j + 1], s2 = ssrc[j + 2], s3 = ssrc[j + 3];
        u32 n0 = hb32[s0 * 32 + li];
        u32 n1 = hb32[s1 * 32 + li];
        u32 n2 = hb32[s2 * 32 + li];
        u32 n3 = hb32[s3 * 32 + li];
        float2 a0 = up2(n0), a1 = up2(n1), a2 = up2(n2), a3 = up2(n3);
        v0 += a0.x + a1.x + a2.x + a3.x;
        v1 += a0.y + a1.y + a2.y + a3.y;
        j += 4;
    }
    for (; j < e; ++j) {
        float2 a = up2(hb32[ssrc[j] * 32 + li]);
        v0 += a.x; v1 += a.y;
    }
    float v = v0 * W1l[2 * li] + v1 * W1l[2 * li + 1];
#pragma unroll
    for (int off = 16; off; off >>= 1) v += __shfl_xor(v, off);  // within 32-lane half
    if (li == 0) {
        float h1 = fmaxf(v + b1l[0], 0.0f);
        o[node] = fmaf(h1, W2l[0], b2l[0]);
    }
}

// ---------------- mean pool ----------------

__global__ __launch_bounds__(256) void k_pool(const float* __restrict__ o,
                                              const int* __restrict__ batch,
                                              float* __restrict__ out) {
    int g = blockIdx.x;
    int lo = 0, hi = N_NODES;
    while (lo < hi) { int mid = (lo + hi) >> 1; if (batch[mid] < g) lo = mid + 1; else hi = mid; }
    int start = lo;
    hi = N_NODES;
    while (lo < hi) { int mid = (lo + hi) >> 1; if (batch[mid] < g + 1) lo = mid + 1; else hi = mid; }
    int end = lo;

    float s = 0.0f;
    for (int i = start + threadIdx.x; i < end; i += 256) s += o[i];
#pragma unroll
    for (int off = 32; off; off >>= 1) s += __shfl_xor(s, off);
    __shared__ float red[4];
    int lane = threadIdx.x & 63, wid = threadIdx.x >> 6;
    if (lane == 0) red[wid] = s;
    __syncthreads();
    if (threadIdx.x == 0) {
        float t = red[0] + red[1] + red[2] + red[3];
        float c = (float)(end - start);
        out[g] = t / fmaxf(c, 1.0f);
    }
}

// ---------------- launch ----------------

extern "C" void kernel_launch(void* const* d_in, const int* in_sizes, int n_in,
                              void* d_out, int out_size, void* d_ws, size_t ws_size,
                              hipStream_t stream) {
    const float* x    = (const float*)d_in[0];
    const int*   ei   = (const int*)d_in[1];   // [2][N_EDGES]
    const int*   bat  = (const int*)d_in[2];
    const float* W1   = (const float*)d_in[3];
    const float* b1   = (const float*)d_in[4];
    const float* W2   = (const float*)d_in[5];
    const float* b2   = (const float*)d_in[6];
    const float* W1l  = (const float*)d_in[7];
    const float* b1l  = (const float*)d_in[8];
    const float* W2l  = (const float*)d_in[9];
    const float* b2l  = (const float*)d_in[10];
    float* out = (float*)d_out;

    const int* srcI = ei;            // row 0
    const int* dstI = ei + N_EDGES;  // row 1

    // workspace carve-up (all 16B-aligned)
    char* ws = (char*)d_ws;
    u32*   aggb  = (u32*)ws;                                ws += (size_t)N_NODES * 32 * 4;
    u16*   hb    = (u16*)ws;                                ws += (size_t)N_NODES * FEAT * 2;
    int*   offs  = (int*)ws;                                ws += (size_t)N_NODES * 4;
    int*   ssrc  = (int*)ws;                                ws += (size_t)N_EDGES * 4;
    int*   tmp   = (int*)ws;                                ws += (size_t)NCB * CB_CAP * 4;
    float* onode = (float*)ws;                              ws += (size_t)N_NODES * 4;
    int*   bsum  = (int*)ws;                                ws += 128 * 4;
    int*   bhist = (int*)ws;                                ws += (size_t)NCB * PB * 4;
    int*   gtot  = (int*)ws;                                ws += ((NCB + 3) & ~3) * 4;

    k_phist<<<PB, 256, 0, stream>>>(dstI, bhist);
    k_pscan<<<NCB, PB, 0, stream>>>(bhist, gtot);
    k_pscatter<<<PB, 256, 0, stream>>>(srcI, dstI, bhist, tmp);
    k_bdeg<<<NCB, 256, 0, stream>>>(tmp, gtot, offs);
    k_scan1<<<SCAN_BLOCKS, 256, 0, stream>>>(offs, bsum);
    k_scan2<<<1, 128, 0, stream>>>(bsum);
    k_scan3<<<SCAN_BLOCKS, 256, 0, stream>>>(offs, bsum);
    k_bsort<<<NCB, 256, 0, stream>>>(tmp, offs, gtot, ssrc);
    k_cvt<<<(N_NODES * FEAT / 8 + 255) / 256, 256, 0, stream>>>(x, hb);

    const int ngrid = (N_NODES + 7) / 8;      // aggregate: 8 nodes (2 per wave) per block
    const int mgrid = (N_NODES + 255) / 256;  // mlp: thread per node

    for (int l = 0; l < 4; ++l) {
        k_aggregate<<<ngrid, 256, 0, stream>>>(hb, aggb, offs, ssrc);
        k_mlp<true><<<mgrid, 256, 0, stream>>>(aggb, hb,
                                               W1 + (size_t)l * FEAT * FEAT,
                                               b1 + (size_t)l * FEAT,
                                               W2 + (size_t)l * FEAT * FEAT,
                                               b2 + (size_t)l * FEAT);
    }
    k_lastagg<<<ngrid, 256, 0, stream>>>(hb, offs, ssrc, W1l, b1l, W2l, b2l, onode);
    k_pool<<<NGRAPH, 256, 0, stream>>>(onode, bat, out);
}

// Round 10
// 435.680 us; speedup vs baseline: 1.5734x; 1.5734x over previous
//
#include <hip/hip_runtime.h>
#include <hip/hip_bf16.h>

#define N_NODES 100000
#define N_EDGES 1600000
#define FEAT 64
#define NGRAPH 256

#define SCAN_CHUNK 1024
#define SCAN_BLOCKS ((N_NODES + SCAN_CHUNK - 1) / SCAN_CHUNK)  // 98

// coarse buckets: 1024 nodes each
#define CB_SHIFT 10
#define CB_NODES 1024
#define NCB ((N_NODES + CB_NODES - 1) / CB_NODES)   // 98
#define CB_CAP 18432                                 // slots per bucket

#define PB 512                                       // partition blocks
#define EPB ((N_EDGES + PB - 1) / PB)                // 3125 edges per block

typedef unsigned short u16;
typedef unsigned int u32;

static __device__ __forceinline__ float bf2f(u16 h) {
    return __uint_as_float(((u32)h) << 16);
}
static __device__ __forceinline__ u16 f2bf(float x) {  // round-to-nearest-even (finite)
    u32 u = __float_as_uint(x);
    return (u16)((u + 0x7FFF + ((u >> 16) & 1)) >> 16);
}
static __device__ __forceinline__ float2 up2(u32 v) {
    return make_float2(bf2f((u16)(v & 0xFFFF)), bf2f((u16)(v >> 16)));
}

// ---------------- two-pass multisplit partition into coarse buckets ----------------

__global__ __launch_bounds__(256) void k_phist(const int* __restrict__ dst,
                                               int* __restrict__ bhist) {
    __shared__ int cnt[NCB];
    int t = threadIdx.x;
    for (int i = t; i < NCB; i += 256) cnt[i] = 0;
    __syncthreads();
    int begin = blockIdx.x * EPB;
    int end = begin + EPB; if (end > N_EDGES) end = N_EDGES;
    for (int e = begin + t; e < end; e += 256)
        atomicAdd(&cnt[dst[e] >> CB_SHIFT], 1);
    __syncthreads();
    for (int i = t; i < NCB; i += 256) bhist[i * PB + blockIdx.x] = cnt[i];
}

__global__ __launch_bounds__(PB) void k_pscan(int* __restrict__ bhist,
                                              int* __restrict__ gtot) {
    __shared__ int s[PB];
    int b = blockIdx.x, t = threadIdx.x;
    int v = bhist[b * PB + t];
    s[t] = v;
    __syncthreads();
    for (int off = 1; off < PB; off <<= 1) {
        int add = (t >= off) ? s[t - off] : 0;
        __syncthreads();
        s[t] += add;
        __syncthreads();
    }
    int incl = s[t];
    bhist[b * PB + t] = (t ? s[t - 1] : 0);
    if (t == PB - 1) gtot[b] = incl;
}

__global__ __launch_bounds__(256) void k_pscatter(const int* __restrict__ src,
                                                  const int* __restrict__ dst,
                                                  const int* __restrict__ bhist,
                                                  int* __restrict__ tmp) {
    __shared__ int cur[NCB];
    int t = threadIdx.x;
    for (int i = t; i < NCB; i += 256) cur[i] = bhist[i * PB + blockIdx.x];
    __syncthreads();
    int begin = blockIdx.x * EPB;
    int end = begin + EPB; if (end > N_EDGES) end = N_EDGES;
    for (int e = begin + t; e < end; e += 256) {
        int d = dst[e];
        int b = d >> CB_SHIFT;
        int pos = atomicAdd(&cur[b], 1);
        if (pos < CB_CAP) tmp[b * CB_CAP + pos] = ((d & (CB_NODES - 1)) << 17) | src[e];
    }
}

// ---------------- per-bucket degree count ----------------

__global__ __launch_bounds__(256) void k_bdeg(const int* __restrict__ tmp,
                                              const int* __restrict__ gtot,
                                              int* __restrict__ deg) {
    __shared__ int cnt[CB_NODES];
    int b = blockIdx.x, t = threadIdx.x;
    for (int j = t; j < CB_NODES; j += 256) cnt[j] = 0;
    __syncthreads();
    int n = gtot[b]; if (n > CB_CAP) n = CB_CAP;
    const int* tp = &tmp[b * CB_CAP];
    for (int i = t; i < n; i += 256) atomicAdd(&cnt[tp[i] >> 17], 1);
    __syncthreads();
    int n0 = b << CB_SHIFT;
    for (int j = t; j < CB_NODES; j += 256) {
        int node = n0 + j;
        if (node < N_NODES) deg[node] = cnt[j];
    }
}

// ---------------- CSR offset scan ----------------

__global__ __launch_bounds__(256) void k_scan1(const int* __restrict__ deg,
                                               int* __restrict__ bsum) {
    int t = threadIdx.x;
    int base = blockIdx.x * SCAN_CHUNK + t * 4;
    int4 d = make_int4(0, 0, 0, 0);
    if (base + 3 < N_NODES) {
        d = *reinterpret_cast<const int4*>(&deg[base]);
    } else {
        if (base + 0 < N_NODES) d.x = deg[base + 0];
        if (base + 1 < N_NODES) d.y = deg[base + 1];
        if (base + 2 < N_NODES) d.z = deg[base + 2];
    }
    int v = d.x + d.y + d.z + d.w;
#pragma unroll
    for (int off = 32; off; off >>= 1) v += __shfl_xor(v, off);
    __shared__ int red[4];
    int lane = t & 63, wid = t >> 6;
    if (lane == 0) red[wid] = v;
    __syncthreads();
    if (t == 0) bsum[blockIdx.x] = red[0] + red[1] + red[2] + red[3];
}

__global__ __launch_bounds__(128) void k_scan2(int* __restrict__ bsum) {
    __shared__ int s[128];
    int t = threadIdx.x;
    int v = (t < SCAN_BLOCKS) ? bsum[t] : 0;
    s[t] = v;
    __syncthreads();
    for (int off = 1; off < 128; off <<= 1) {
        int add = (t >= off) ? s[t - off] : 0;
        __syncthreads();
        s[t] += add;
        __syncthreads();
    }
    if (t < SCAN_BLOCKS) bsum[t] = (t ? s[t - 1] : 0);
}

__global__ __launch_bounds__(256) void k_scan3(int* __restrict__ deg_off,
                                               const int* __restrict__ bsum) {
    int t = threadIdx.x;
    int base = blockIdx.x * SCAN_CHUNK + t * 4;
    int4 d = make_int4(0, 0, 0, 0);
    bool full = (base + 3 < N_NODES);
    if (full) {
        d = *reinterpret_cast<const int4*>(&deg_off[base]);
    } else {
        if (base + 0 < N_NODES) d.x = deg_off[base + 0];
        if (base + 1 < N_NODES) d.y = deg_off[base + 1];
        if (base + 2 < N_NODES) d.z = deg_off[base + 2];
    }
    int total = d.x + d.y + d.z + d.w;
    __shared__ int sc[256];
    sc[t] = total;
    __syncthreads();
    for (int off = 1; off < 256; off <<= 1) {
        int add = (t >= off) ? sc[t - off] : 0;
        __syncthreads();
        sc[t] += add;
        __syncthreads();
    }
    int texc = (t ? sc[t - 1] : 0) + bsum[blockIdx.x];
    int4 o;
    o.x = texc;
    o.y = o.x + d.x;
    o.z = o.y + d.y;
    o.w = o.z + d.z;
    if (full) {
        *reinterpret_cast<int4*>(&deg_off[base]) = o;
    } else {
        if (base + 0 < N_NODES) deg_off[base + 0] = o.x;
        if (base + 1 < N_NODES) deg_off[base + 1] = o.y;
        if (base + 2 < N_NODES) deg_off[base + 2] = o.z;
    }
}

// ---------------- per-bucket scatter into CSR order ----------------

__global__ __launch_bounds__(256) void k_bsort(const int* __restrict__ tmp,
                                               const int* __restrict__ offs,
                                               const int* __restrict__ gtot,
                                               int* __restrict__ ssrc) {
    __shared__ int lcur[CB_NODES];
    int b = blockIdx.x;
    int n0 = b << CB_SHIFT;
    int t = threadIdx.x;
    for (int j = t; j < CB_NODES; j += 256) {
        int n = n0 + j;
        lcur[j] = (n < N_NODES) ? offs[n] : 0;
    }
    __syncthreads();
    int cnt = gtot[b]; if (cnt > CB_CAP) cnt = CB_CAP;
    const int* tp = &tmp[b * CB_CAP];
    for (int i = t; i < cnt; i += 256) {
        int p = tp[i];
        int pos = atomicAdd(&lcur[p >> 17], 1);
        ssrc[pos] = p & 0x1FFFF;
    }
}

// ---------------- x (f32) -> bf16 node table ----------------

__global__ __launch_bounds__(256) void k_cvt(const float* __restrict__ x,
                                             u16* __restrict__ hb) {
    int i = blockIdx.x * 256 + threadIdx.x;  // 8 elems each
    const int total = N_NODES * FEAT / 8;
    if (i < total) {
        const float4* xv = (const float4*)x;
        float4 a = xv[2 * i], b = xv[2 * i + 1];
        uint4 o;
        o.x = f2bf(a.x) | ((u32)f2bf(a.y) << 16);
        o.y = f2bf(a.z) | ((u32)f2bf(a.w) << 16);
        o.z = f2bf(b.x) | ((u32)f2bf(b.y) << 16);
        o.w = f2bf(b.z) | ((u32)f2bf(b.w) << 16);
        ((uint4*)hb)[i] = o;
    }
}

// ---------------- GIN aggregation: 2 nodes/wave, unroll-8 gather pipeline, f32 out ----------------

__global__ __launch_bounds__(256) void k_aggregate(const u16* __restrict__ hb,
                                                   float* __restrict__ agg,
                                                   const int* __restrict__ offs,
                                                   const int* __restrict__ ssrc) {
    int w = threadIdx.x >> 6;
    int lane = threadIdx.x & 63;
    int half = lane >> 5;
    int li = lane & 31;
    int node = blockIdx.x * 8 + w * 2 + half;
    if (node >= N_NODES) return;
    const u32* hb32 = (const u32*)hb;
    float2 p = up2(hb32[node * 32 + li]);
    float v0 = p.x, v1 = p.y;
    int s = offs[node];
    int e = (node + 1 < N_NODES) ? offs[node + 1] : N_EDGES;
    int j = s;
    for (; j + 7 < e; j += 8) {
        int s0 = ssrc[j], s1 = ssrc[j + 1], s2 = ssrc[j + 2], s3 = ssrc[j + 3];
        int s4 = ssrc[j + 4], s5 = ssrc[j + 5], s6 = ssrc[j + 6], s7 = ssrc[j + 7];
        u32 n0 = hb32[s0 * 32 + li];
        u32 n1 = hb32[s1 * 32 + li];
        u32 n2 = hb32[s2 * 32 + li];
        u32 n3 = hb32[s3 * 32 + li];
        u32 n4 = hb32[s4 * 32 + li];
        u32 n5 = hb32[s5 * 32 + li];
        u32 n6 = hb32[s6 * 32 + li];
        u32 n7 = hb32[s7 * 32 + li];
        float2 a0 = up2(n0), a1 = up2(n1), a2 = up2(n2), a3 = up2(n3);
        float2 a4 = up2(n4), a5 = up2(n5), a6 = up2(n6), a7 = up2(n7);
        v0 += a0.x + a1.x + a2.x + a3.x + a4.x + a5.x + a6.x + a7.x;
        v1 += a0.y + a1.y + a2.y + a3.y + a4.y + a5.y + a6.y + a7.y;
    }
    if (j + 3 < e) {
        int s0 = ssrc[j], s1 = ssrc[j + 1], s2 = ssrc[j + 2], s3 = ssrc[j + 3];
        u32 n0 = hb32[s0 * 32 + li];
        u32 n1 = hb32[s1 * 32 + li];
        u32 n2 = hb32[s2 * 32 + li];
        u32 n3 = hb32[s3 * 32 + li];
        float2 a0 = up2(n0), a1 = up2(n1), a2 = up2(n2), a3 = up2(n3);
        v0 += a0.x + a1.x + a2.x + a3.x;
        v1 += a0.y + a1.y + a2.y + a3.y;
        j += 4;
    }
    for (; j < e; ++j) {
        float2 a = up2(hb32[ssrc[j] * 32 + li]);
        v0 += a.x; v1 += a.y;
    }
    float2* outp = (float2*)(agg + (size_t)node * FEAT);
    outp[li] = make_float2(v0, v1);
}

// ---------------- fused 64->64->64 MLP (f32 in/math, bf16 output table) ----------------
// EXACT R8 codegen: 128 VGPR, ~20% occupancy. Do not reintroduce bf16 input here
// without a packed-register redesign (R9: VGPR 256 -> occupancy 8.6% -> 2x slower).

template <bool RELU_OUT>
__global__ __launch_bounds__(256) void k_mlp(const float* __restrict__ agg,
                                             u16* __restrict__ hout,
                                             const float* __restrict__ W1,
                                             const float* __restrict__ b1,
                                             const float* __restrict__ W2,
                                             const float* __restrict__ b2) {
    __shared__ float w1s[FEAT * FEAT];
    __shared__ float w2s[FEAT * FEAT];
    __shared__ float b1s[FEAT];
    __shared__ float b2s[FEAT];
    {
        const float4* W1v = (const float4*)W1;
        const float4* W2v = (const float4*)W2;
        float4* w1sv = (float4*)w1s;
        float4* w2sv = (float4*)w2s;
        for (int i = threadIdx.x; i < FEAT * FEAT / 4; i += 256) {
            w1sv[i] = W1v[i];
            w2sv[i] = W2v[i];
        }
        if (threadIdx.x < FEAT) {
            b1s[threadIdx.x] = b1[threadIdx.x];
            b2s[threadIdx.x] = b2[threadIdx.x];
        }
    }
    __syncthreads();

    int node = blockIdx.x * 256 + threadIdx.x;
    if (node >= N_NODES) return;

    float a[FEAT], h[FEAT];
    const float4* av = (const float4*)(agg + (size_t)node * FEAT);
#pragma unroll
    for (int q = 0; q < FEAT / 4; ++q) {
        float4 v = av[q];
        a[4 * q + 0] = v.x; a[4 * q + 1] = v.y; a[4 * q + 2] = v.z; a[4 * q + 3] = v.w;
    }

    const float4* w1v = (const float4*)w1s;
    const float4* b1v = (const float4*)b1s;
#pragma unroll
    for (int q = 0; q < FEAT / 4; ++q) {
        float4 b = b1v[q];
        h[4 * q + 0] = b.x; h[4 * q + 1] = b.y; h[4 * q + 2] = b.z; h[4 * q + 3] = b.w;
    }
#pragma unroll
    for (int k = 0; k < FEAT; ++k) {
        float ak = a[k];
#pragma unroll
        for (int q = 0; q < FEAT / 4; ++q) {
            float4 w = w1v[k * (FEAT / 4) + q];
            h[4 * q + 0] = fmaf(ak, w.x, h[4 * q + 0]);
            h[4 * q + 1] = fmaf(ak, w.y, h[4 * q + 1]);
            h[4 * q + 2] = fmaf(ak, w.z, h[4 * q + 2]);
            h[4 * q + 3] = fmaf(ak, w.w, h[4 * q + 3]);
        }
    }
#pragma unroll
    for (int j = 0; j < FEAT; ++j) h[j] = fmaxf(h[j], 0.0f);

    const float4* w2v = (const float4*)w2s;
    const float4* b2v = (const float4*)b2s;
#pragma unroll
    for (int q = 0; q < FEAT / 4; ++q) {
        float4 b = b2v[q];
        a[4 * q + 0] = b.x; a[4 * q + 1] = b.y; a[4 * q + 2] = b.z; a[4 * q + 3] = b.w;
    }
#pragma unroll
    for (int k = 0; k < FEAT; ++k) {
        float hk = h[k];
#pragma unroll
        for (int q = 0; q < FEAT / 4; ++q) {
            float4 w = w2v[k * (FEAT / 4) + q];
            a[4 * q + 0] = fmaf(hk, w.x, a[4 * q + 0]);
            a[4 * q + 1] = fmaf(hk, w.y, a[4 * q + 1]);
            a[4 * q + 2] = fmaf(hk, w.z, a[4 * q + 2]);
            a[4 * q + 3] = fmaf(hk, w.w, a[4 * q + 3]);
        }
    }
    if (RELU_OUT) {
#pragma unroll
        for (int j = 0; j < FEAT; ++j) a[j] = fmaxf(a[j], 0.0f);
    }

    u32 w[FEAT / 2];
#pragma unroll
    for (int q = 0; q < FEAT / 2; ++q)
        w[q] = f2bf(a[2 * q]) | ((u32)f2bf(a[2 * q + 1]) << 16);
    uint4* ov = (uint4*)(hout + (size_t)node * FEAT);
#pragma unroll
    for (int q = 0; q < FEAT / 8; ++q)
        ov[q] = make_uint4(w[4 * q + 0], w[4 * q + 1], w[4 * q + 2], w[4 * q + 3]);
}

// ---------------- last layer: fused aggregate + (64->1->1), unroll-8 ----------------

__global__ __launch_bounds__(256) void k_lastagg(const u16* __restrict__ hb,
                                                 const int* __restrict__ offs,
                                                 const int* __restrict__ ssrc,
                                                 const float* __restrict__ W1l,
                                                 const float* __restrict__ b1l,
                                                 const float* __restrict__ W2l,
                                                 const float* __restrict__ b2l,
                                                 float* __restrict__ o) {
    int w = threadIdx.x >> 6;
    int lane = threadIdx.x & 63;
    int half = lane >> 5;
    int li = lane & 31;
    int node = blockIdx.x * 8 + w * 2 + half;
    if (node >= N_NODES) return;
    const u32* hb32 = (const u32*)hb;
    float2 p = up2(hb32[node * 32 + li]);
    float v0 = p.x, v1 = p.y;
    int s = offs[node];
    int e = (node + 1 < N_NODES) ? offs[node + 1] : N_EDGES;
    int j = s;
    for (; j + 7 < e; j += 8) {
        int s0 = ssrc[j], s1 = ssrc[j + 1], s2 = ssrc[j + 2], s3 = ssrc[j + 3];
        int s4 = ssrc[j + 4], s5 = ssrc[j + 5], s6 = ssrc[j + 6], s7 = ssrc[j + 7];
        u32 n0 = hb32[s0 * 32 + li];
        u32 n1 = hb32[s1 * 32 + li];
        u32 n2 = hb32[s2 * 32 + li];
        u32 n3 = hb32[s3 * 32 + li];
        u32 n4 = hb32[s4 * 32 + li];
        u32 n5 = hb32[s5 * 32 + li];
        u32 n6 = hb32[s6 * 32 + li];
        u32 n7 = hb32[s7 * 32 + li];
        float2 a0 = up2(n0), a1 = up2(n1), a2 = up2(n2), a3 = up2(n3);
        float2 a4 = up2(n4), a5 = up2(n5), a6 = up2(n6), a7 = up2(n7);
        v0 += a0.x + a1.x + a2.x + a3.x + a4.x + a5.x + a6.x + a7.x;
        v1 += a0.y + a1.y + a2.y + a3.y + a4.y + a5.y + a6.y + a7.y;
    }
    if (j + 3 < e) {
        int s0 = ssrc[j], s1 = ssrc[j + 1], s2 = ssrc[j + 2], s3 = ssrc[j + 3];
        u32 n0 = hb32[s0 * 32 + li];
        u32 n1 = hb32[s1 * 32 + li];
        u32 n2 = hb32[s2 * 32 + li];
        u32 n3 = hb32[s3 * 32 + li];
        float2 a0 = up2(n0), a1 = up2(n1), a2 = up2(n2), a3 = up2(n3);
        v0 += a0.x + a1.x + a2.x + a3.x;
        v1 += a0.y + a1.y + a2.y + a3.y;
        j += 4;
    }
    for (; j < e; ++j) {
        float2 a = up2(hb32[ssrc[j] * 32 + li]);
        v0 += a.x; v1 += a.y;
    }
    float v = v0 * W1l[2 * li] + v1 * W1l[2 * li + 1];
#pragma unroll
    for (int off = 16; off; off >>= 1) v += __shfl_xor(v, off);  // within 32-lane half
    if (li == 0) {
        float h1 = fmaxf(v + b1l[0], 0.0f);
        o[node] = fmaf(h1, W2l[0], b2l[0]);
    }
}

// ---------------- mean pool ----------------

__global__ __launch_bounds__(256) void k_pool(const float* __restrict__ o,
                                              const int* __restrict__ batch,
                                              float* __restrict__ out) {
    int g = blockIdx.x;
    int lo = 0, hi = N_NODES;
    while (lo < hi) { int mid = (lo + hi) >> 1; if (batch[mid] < g) lo = mid + 1; else hi = mid; }
    int start = lo;
    hi = N_NODES;
    while (lo < hi) { int mid = (lo + hi) >> 1; if (batch[mid] < g + 1) lo = mid + 1; else hi = mid; }
    int end = lo;

    float s = 0.0f;
    for (int i = start + threadIdx.x; i < end; i += 256) s += o[i];
#pragma unroll
    for (int off = 32; off; off >>= 1) s += __shfl_xor(s, off);
    __shared__ float red[4];
    int lane = threadIdx.x & 63, wid = threadIdx.x >> 6;
    if (lane == 0) red[wid] = s;
    __syncthreads();
    if (threadIdx.x == 0) {
        float t = red[0] + red[1] + red[2] + red[3];
        float c = (float)(end - start);
        out[g] = t / fmaxf(c, 1.0f);
    }
}

// ---------------- launch ----------------

extern "C" void kernel_launch(void* const* d_in, const int* in_sizes, int n_in,
                              void* d_out, int out_size, void* d_ws, size_t ws_size,
                              hipStream_t stream) {
    const float* x    = (const float*)d_in[0];
    const int*   ei   = (const int*)d_in[1];   // [2][N_EDGES]
    const int*   bat  = (const int*)d_in[2];
    const float* W1   = (const float*)d_in[3];
    const float* b1   = (const float*)d_in[4];
    const float* W2   = (const float*)d_in[5];
    const float* b2   = (const float*)d_in[6];
    const float* W1l  = (const float*)d_in[7];
    const float* b1l  = (const float*)d_in[8];
    const float* W2l  = (const float*)d_in[9];
    const float* b2l  = (const float*)d_in[10];
    float* out = (float*)d_out;

    const int* srcI = ei;            // row 0
    const int* dstI = ei + N_EDGES;  // row 1

    // workspace carve-up (all 16B-aligned)
    char* ws = (char*)d_ws;
    float* agg   = (float*)ws;                              ws += (size_t)N_NODES * FEAT * 4;
    u16*   hb    = (u16*)ws;                                ws += (size_t)N_NODES * FEAT * 2;
    int*   offs  = (int*)ws;                                ws += (size_t)N_NODES * 4;
    int*   ssrc  = (int*)ws;                                ws += (size_t)N_EDGES * 4;
    int*   tmp   = (int*)ws;                                ws += (size_t)NCB * CB_CAP * 4;
    float* onode = (float*)ws;                              ws += (size_t)N_NODES * 4;
    int*   bsum  = (int*)ws;                                ws += 128 * 4;
    int*   bhist = (int*)ws;                                ws += (size_t)NCB * PB * 4;
    int*   gtot  = (int*)ws;                                ws += ((NCB + 3) & ~3) * 4;

    k_phist<<<PB, 256, 0, stream>>>(dstI, bhist);
    k_pscan<<<NCB, PB, 0, stream>>>(bhist, gtot);
    k_pscatter<<<PB, 256, 0, stream>>>(srcI, dstI, bhist, tmp);
    k_bdeg<<<NCB, 256, 0, stream>>>(tmp, gtot, offs);
    k_scan1<<<SCAN_BLOCKS, 256, 0, stream>>>(offs, bsum);
    k_scan2<<<1, 128, 0, stream>>>(bsum);
    k_scan3<<<SCAN_BLOCKS, 256, 0, stream>>>(offs, bsum);
    k_bsort<<<NCB, 256, 0, stream>>>(tmp, offs, gtot, ssrc);
    k_cvt<<<(N_NODES * FEAT / 8 + 255) / 256, 256, 0, stream>>>(x, hb);

    const int ngrid = (N_NODES + 7) / 8;      // aggregate: 8 nodes (2 per wave) per block
    const int mgrid = (N_NODES + 255) / 256;  // mlp: thread per node

    for (int l = 0; l < 4; ++l) {
        k_aggregate<<<ngrid, 256, 0, stream>>>(hb, agg, offs, ssrc);
        k_mlp<true><<<mgrid, 256, 0, stream>>>(agg, hb,
                                               W1 + (size_t)l * FEAT * FEAT,
                                               b1 + (size_t)l * FEAT,
                                               W2 + (size_t)l * FEAT * FEAT,
                                               b2 + (size_t)l * FEAT);
    }
    k_lastagg<<<ngrid, 256, 0, stream>>>(hb, offs, ssrc, W1l, b1l, W2l, b2l, onode);
    k_pool<<<NGRAPH, 256, 0, stream>>>(onode, bat, out);
}

// Round 11
// 323.024 us; speedup vs baseline: 2.1221x; 1.3488x over previous
//
#include <hip/hip_runtime.h>
#include <hip/hip_bf16.h>

#define N_NODES 100000
#define N_EDGES 1600000
#define FEAT 64
#define NGRAPH 256

#define SCAN_CHUNK 1024
#define SCAN_BLOCKS ((N_NODES + SCAN_CHUNK - 1) / SCAN_CHUNK)  // 98

// coarse buckets: 1024 nodes each
#define CB_SHIFT 10
#define CB_NODES 1024
#define NCB ((N_NODES + CB_NODES - 1) / CB_NODES)   // 98
#define CB_CAP 18432                                 // slots per bucket

#define PB 512                                       // partition blocks
#define EPB ((N_EDGES + PB - 1) / PB)                // 3125 edges per block

#define NTILES (N_NODES / 16)                        // 6250 (exact)
#define MLP_BLOCKS 1024

typedef unsigned short u16;
typedef unsigned int u32;
typedef __attribute__((ext_vector_type(8))) short short8;
typedef __attribute__((ext_vector_type(4))) float f32x4;

static __device__ __forceinline__ float bf2f(u16 h) {
    return __uint_as_float(((u32)h) << 16);
}
static __device__ __forceinline__ u16 f2bf(float x) {  // round-to-nearest-even (finite)
    u32 u = __float_as_uint(x);
    return (u16)((u + 0x7FFF + ((u >> 16) & 1)) >> 16);
}
static __device__ __forceinline__ float2 up2(u32 v) {
    return make_float2(bf2f((u16)(v & 0xFFFF)), bf2f((u16)(v >> 16)));
}
static __device__ __forceinline__ short8 as_short8(uint4 v) {
    union { uint4 u; short8 s; } c; c.u = v; return c.s;
}

// ---------------- two-pass multisplit partition into coarse buckets ----------------

__global__ __launch_bounds__(256) void k_phist(const int* __restrict__ dst,
                                               int* __restrict__ bhist) {
    __shared__ int cnt[NCB];
    int t = threadIdx.x;
    for (int i = t; i < NCB; i += 256) cnt[i] = 0;
    __syncthreads();
    int begin = blockIdx.x * EPB;
    int end = begin + EPB; if (end > N_EDGES) end = N_EDGES;
    for (int e = begin + t; e < end; e += 256)
        atomicAdd(&cnt[dst[e] >> CB_SHIFT], 1);
    __syncthreads();
    for (int i = t; i < NCB; i += 256) bhist[i * PB + blockIdx.x] = cnt[i];
}

__global__ __launch_bounds__(PB) void k_pscan(int* __restrict__ bhist,
                                              int* __restrict__ gtot) {
    __shared__ int s[PB];
    int b = blockIdx.x, t = threadIdx.x;
    int v = bhist[b * PB + t];
    s[t] = v;
    __syncthreads();
    for (int off = 1; off < PB; off <<= 1) {
        int add = (t >= off) ? s[t - off] : 0;
        __syncthreads();
        s[t] += add;
        __syncthreads();
    }
    int incl = s[t];
    bhist[b * PB + t] = (t ? s[t - 1] : 0);
    if (t == PB - 1) gtot[b] = incl;
}

__global__ __launch_bounds__(256) void k_pscatter(const int* __restrict__ src,
                                                  const int* __restrict__ dst,
                                                  const int* __restrict__ bhist,
                                                  int* __restrict__ tmp) {
    __shared__ int cur[NCB];
    int t = threadIdx.x;
    for (int i = t; i < NCB; i += 256) cur[i] = bhist[i * PB + blockIdx.x];
    __syncthreads();
    int begin = blockIdx.x * EPB;
    int end = begin + EPB; if (end > N_EDGES) end = N_EDGES;
    for (int e = begin + t; e < end; e += 256) {
        int d = dst[e];
        int b = d >> CB_SHIFT;
        int pos = atomicAdd(&cur[b], 1);
        if (pos < CB_CAP) tmp[b * CB_CAP + pos] = ((d & (CB_NODES - 1)) << 17) | src[e];
    }
}

// ---------------- per-bucket degree count ----------------

__global__ __launch_bounds__(256) void k_bdeg(const int* __restrict__ tmp,
                                              const int* __restrict__ gtot,
                                              int* __restrict__ deg) {
    __shared__ int cnt[CB_NODES];
    int b = blockIdx.x, t = threadIdx.x;
    for (int j = t; j < CB_NODES; j += 256) cnt[j] = 0;
    __syncthreads();
    int n = gtot[b]; if (n > CB_CAP) n = CB_CAP;
    const int* tp = &tmp[b * CB_CAP];
    for (int i = t; i < n; i += 256) atomicAdd(&cnt[tp[i] >> 17], 1);
    __syncthreads();
    int n0 = b << CB_SHIFT;
    for (int j = t; j < CB_NODES; j += 256) {
        int node = n0 + j;
        if (node < N_NODES) deg[node] = cnt[j];
    }
}

// ---------------- CSR offset scan ----------------

__global__ __launch_bounds__(256) void k_scan1(const int* __restrict__ deg,
                                               int* __restrict__ bsum) {
    int t = threadIdx.x;
    int base = blockIdx.x * SCAN_CHUNK + t * 4;
    int4 d = make_int4(0, 0, 0, 0);
    if (base + 3 < N_NODES) {
        d = *reinterpret_cast<const int4*>(&deg[base]);
    } else {
        if (base + 0 < N_NODES) d.x = deg[base + 0];
        if (base + 1 < N_NODES) d.y = deg[base + 1];
        if (base + 2 < N_NODES) d.z = deg[base + 2];
    }
    int v = d.x + d.y + d.z + d.w;
#pragma unroll
    for (int off = 32; off; off >>= 1) v += __shfl_xor(v, off);
    __shared__ int red[4];
    int lane = t & 63, wid = t >> 6;
    if (lane == 0) red[wid] = v;
    __syncthreads();
    if (t == 0) bsum[blockIdx.x] = red[0] + red[1] + red[2] + red[3];
}

__global__ __launch_bounds__(128) void k_scan2(int* __restrict__ bsum) {
    __shared__ int s[128];
    int t = threadIdx.x;
    int v = (t < SCAN_BLOCKS) ? bsum[t] : 0;
    s[t] = v;
    __syncthreads();
    for (int off = 1; off < 128; off <<= 1) {
        int add = (t >= off) ? s[t - off] : 0;
        __syncthreads();
        s[t] += add;
        __syncthreads();
    }
    if (t < SCAN_BLOCKS) bsum[t] = (t ? s[t - 1] : 0);
}

__global__ __launch_bounds__(256) void k_scan3(int* __restrict__ deg_off,
                                               const int* __restrict__ bsum) {
    int t = threadIdx.x;
    int base = blockIdx.x * SCAN_CHUNK + t * 4;
    int4 d = make_int4(0, 0, 0, 0);
    bool full = (base + 3 < N_NODES);
    if (full) {
        d = *reinterpret_cast<const int4*>(&deg_off[base]);
    } else {
        if (base + 0 < N_NODES) d.x = deg_off[base + 0];
        if (base + 1 < N_NODES) d.y = deg_off[base + 1];
        if (base + 2 < N_NODES) d.z = deg_off[base + 2];
    }
    int total = d.x + d.y + d.z + d.w;
    __shared__ int sc[256];
    sc[t] = total;
    __syncthreads();
    for (int off = 1; off < 256; off <<= 1) {
        int add = (t >= off) ? sc[t - off] : 0;
        __syncthreads();
        sc[t] += add;
        __syncthreads();
    }
    int texc = (t ? sc[t - 1] : 0) + bsum[blockIdx.x];
    int4 o;
    o.x = texc;
    o.y = o.x + d.x;
    o.z = o.y + d.y;
    o.w = o.z + d.z;
    if (full) {
        *reinterpret_cast<int4*>(&deg_off[base]) = o;
    } else {
        if (base + 0 < N_NODES) deg_off[base + 0] = o.x;
        if (base + 1 < N_NODES) deg_off[base + 1] = o.y;
        if (base + 2 < N_NODES) deg_off[base + 2] = o.z;
    }
}

// ---------------- per-bucket scatter into CSR order ----------------

__global__ __launch_bounds__(256) void k_bsort(const int* __restrict__ tmp,
                                               const int* __restrict__ offs,
                                               const int* __restrict__ gtot,
                                               int* __restrict__ ssrc) {
    __shared__ int lcur[CB_NODES];
    int b = blockIdx.x;
    int n0 = b << CB_SHIFT;
    int t = threadIdx.x;
    for (int j = t; j < CB_NODES; j += 256) {
        int n = n0 + j;
        lcur[j] = (n < N_NODES) ? offs[n] : 0;
    }
    __syncthreads();
    int cnt = gtot[b]; if (cnt > CB_CAP) cnt = CB_CAP;
    const int* tp = &tmp[b * CB_CAP];
    for (int i = t; i < cnt; i += 256) {
        int p = tp[i];
        int pos = atomicAdd(&lcur[p >> 17], 1);
        ssrc[pos] = p & 0x1FFFF;
    }
}

// ---------------- x (f32) -> bf16 node table ----------------

__global__ __launch_bounds__(256) void k_cvt(const float* __restrict__ x,
                                             u16* __restrict__ hb) {
    int i = blockIdx.x * 256 + threadIdx.x;  // 8 elems each
    const int total = N_NODES * FEAT / 8;
    if (i < total) {
        const float4* xv = (const float4*)x;
        float4 a = xv[2 * i], b = xv[2 * i + 1];
        uint4 o;
        o.x = f2bf(a.x) | ((u32)f2bf(a.y) << 16);
        o.y = f2bf(a.z) | ((u32)f2bf(a.w) << 16);
        o.z = f2bf(b.x) | ((u32)f2bf(b.y) << 16);
        o.w = f2bf(b.z) | ((u32)f2bf(b.w) << 16);
        ((uint4*)hb)[i] = o;
    }
}

// ---------------- GIN aggregation: 2 nodes/wave, unroll-8, bf16-packed out ----------------

__global__ __launch_bounds__(256) void k_aggregate(const u16* __restrict__ hb,
                                                   u32* __restrict__ aggb,
                                                   const int* __restrict__ offs,
                                                   const int* __restrict__ ssrc) {
    int w = threadIdx.x >> 6;
    int lane = threadIdx.x & 63;
    int half = lane >> 5;
    int li = lane & 31;
    int node = blockIdx.x * 8 + w * 2 + half;
    if (node >= N_NODES) return;
    const u32* hb32 = (const u32*)hb;
    float2 p = up2(hb32[node * 32 + li]);
    float v0 = p.x, v1 = p.y;
    int s = offs[node];
    int e = (node + 1 < N_NODES) ? offs[node + 1] : N_EDGES;
    int j = s;
    for (; j + 7 < e; j += 8) {
        int s0 = ssrc[j], s1 = ssrc[j + 1], s2 = ssrc[j + 2], s3 = ssrc[j + 3];
        int s4 = ssrc[j + 4], s5 = ssrc[j + 5], s6 = ssrc[j + 6], s7 = ssrc[j + 7];
        u32 n0 = hb32[s0 * 32 + li];
        u32 n1 = hb32[s1 * 32 + li];
        u32 n2 = hb32[s2 * 32 + li];
        u32 n3 = hb32[s3 * 32 + li];
        u32 n4 = hb32[s4 * 32 + li];
        u32 n5 = hb32[s5 * 32 + li];
        u32 n6 = hb32[s6 * 32 + li];
        u32 n7 = hb32[s7 * 32 + li];
        float2 a0 = up2(n0), a1 = up2(n1), a2 = up2(n2), a3 = up2(n3);
        float2 a4 = up2(n4), a5 = up2(n5), a6 = up2(n6), a7 = up2(n7);
        v0 += a0.x + a1.x + a2.x + a3.x + a4.x + a5.x + a6.x + a7.x;
        v1 += a0.y + a1.y + a2.y + a3.y + a4.y + a5.y + a6.y + a7.y;
    }
    if (j + 3 < e) {
        int s0 = ssrc[j], s1 = ssrc[j + 1], s2 = ssrc[j + 2], s3 = ssrc[j + 3];
        u32 n0 = hb32[s0 * 32 + li];
        u32 n1 = hb32[s1 * 32 + li];
        u32 n2 = hb32[s2 * 32 + li];
        u32 n3 = hb32[s3 * 32 + li];
        float2 a0 = up2(n0), a1 = up2(n1), a2 = up2(n2), a3 = up2(n3);
        v0 += a0.x + a1.x + a2.x + a3.x;
        v1 += a0.y + a1.y + a2.y + a3.y;
        j += 4;
    }
    for (; j < e; ++j) {
        float2 a = up2(hb32[ssrc[j] * 32 + li]);
        v0 += a.x; v1 += a.y;
    }
    aggb[node * 32 + li] = f2bf(v0) | ((u32)f2bf(v1) << 16);
}

// ---------------- MFMA fused 64->64->64 MLP ----------------
// Per wave: 16-node tile. Swapped GEMM D[n][m] = sum_k W^T[n][k] * act^T[k][m]:
//   A-frag  = W^T tile (lane: n = nt*16 + (l&15), k = kh*32 + (l>>4)*8 + j)  [registers, loaded once]
//   B-frag  = activations^T (lane: m = l&15, k ascending; = packed-bf16 row read, uint4)
//   D       = col(l&15)=m, row=(l>>4)*4+reg = n  [verified layout, m89/m91]
// Inter-layer + output transposes via per-wave-private LDS staging (no barriers).

__global__ __launch_bounds__(256) void k_mlp(const u32* __restrict__ aggb,
                                             u32* __restrict__ hout32,
                                             const float* __restrict__ W1,
                                             const float* __restrict__ b1,
                                             const float* __restrict__ W2,
                                             const float* __restrict__ b2) {
    __shared__ __align__(16) u32 lds[4 * 2 * 576];  // per wave: H[16][36] + O[16][36] u32
    int wid = threadIdx.x >> 6;
    int lane = threadIdx.x & 63;
    int m = lane & 15;   // node-in-tile (D col / B-frag N)
    int g = lane >> 4;   // lane group
    u32* H = &lds[wid * 2 * 576];
    u32* O = H + 576;

    // Weights as A-fragments (W^T), biases for D rows — loaded once per wave.
    short8 A1[4][2], A2[4][2];
    float bv1[4][4], bv2[4][4];
#pragma unroll
    for (int nt = 0; nt < 4; ++nt) {
        int n = nt * 16 + m;
#pragma unroll
        for (int kh = 0; kh < 2; ++kh) {
            short8 s1, s2;
#pragma unroll
            for (int j = 0; j < 8; ++j) {
                int k = kh * 32 + g * 8 + j;
                s1[j] = (short)f2bf(W1[k * 64 + n]);
                s2[j] = (short)f2bf(W2[k * 64 + n]);
            }
            A1[nt][kh] = s1;
            A2[nt][kh] = s2;
        }
#pragma unroll
        for (int r = 0; r < 4; ++r) {
            bv1[nt][r] = b1[nt * 16 + g * 4 + r];
            bv2[nt][r] = b2[nt * 16 + g * 4 + r];
        }
    }

    int gwave = blockIdx.x * 4 + wid;
    int nwaves = gridDim.x * 4;
    for (int tile = gwave; tile < NTILES; tile += nwaves) {
        int nodeBase = tile * 16;
        // B-frags (agg^T) straight from packed bf16: lane m reads its node row.
        const uint4* bp = (const uint4*)(aggb + (size_t)(nodeBase + m) * 32);
        short8 B0 = as_short8(bp[g]);        // kh=0: u32 idx 4g
        short8 B1f = as_short8(bp[4 + g]);   // kh=1: u32 idx 16+4g

        // layer 1: h^T tiles, bias in C, ReLU, stage to LDS (bf16 pairs)
#pragma unroll
        for (int nt = 0; nt < 4; ++nt) {
            f32x4 acc = { bv1[nt][0], bv1[nt][1], bv1[nt][2], bv1[nt][3] };
            acc = __builtin_amdgcn_mfma_f32_16x16x32_bf16(A1[nt][0], B0, acc, 0, 0, 0);
            acc = __builtin_amdgcn_mfma_f32_16x16x32_bf16(A1[nt][1], B1f, acc, 0, 0, 0);
            float h0 = fmaxf(acc[0], 0.0f), h1 = fmaxf(acc[1], 0.0f);
            float h2 = fmaxf(acc[2], 0.0f), h3 = fmaxf(acc[3], 0.0f);
            H[m * 36 + nt * 8 + g * 2 + 0] = f2bf(h0) | ((u32)f2bf(h1) << 16);
            H[m * 36 + nt * 8 + g * 2 + 1] = f2bf(h2) | ((u32)f2bf(h3) << 16);
        }
        // read h^T as layer-2 B-frags (lane m reads its node's h row, k ascending)
        const uint4* hp = (const uint4*)H;
        short8 HB0 = as_short8(hp[9 * m + g]);      // u32 idx m*36 + 4g
        short8 HB1 = as_short8(hp[9 * m + g + 4]);  // u32 idx m*36 + 16 + 4g

        // layer 2 + outer ReLU, stage output
#pragma unroll
        for (int nt = 0; nt < 4; ++nt) {
            f32x4 acc = { bv2[nt][0], bv2[nt][1], bv2[nt][2], bv2[nt][3] };
            acc = __builtin_amdgcn_mfma_f32_16x16x32_bf16(A2[nt][0], HB0, acc, 0, 0, 0);
            acc = __builtin_amdgcn_mfma_f32_16x16x32_bf16(A2[nt][1], HB1, acc, 0, 0, 0);
            float o0 = fmaxf(acc[0], 0.0f), o1 = fmaxf(acc[1], 0.0f);
            float o2 = fmaxf(acc[2], 0.0f), o3 = fmaxf(acc[3], 0.0f);
            O[m * 36 + nt * 8 + g * 2 + 0] = f2bf(o0) | ((u32)f2bf(o1) << 16);
            O[m * 36 + nt * 8 + g * 2 + 1] = f2bf(o2) | ((u32)f2bf(o3) << 16);
        }
        // coalesced writeback: lane covers node m2=l>>2, u32 cols q..q+7
        int m2 = lane >> 2;
        int q = (lane & 3) * 8;
        const uint4* op = (const uint4*)O;
        uint4 w0 = op[(m2 * 36 + q) >> 2];
        uint4 w1 = op[(m2 * 36 + q + 4) >> 2];
        uint4* gp = (uint4*)(hout32 + (size_t)(nodeBase + m2) * 32 + q);
        gp[0] = w0;
        gp[1] = w1;
    }
}

// ---------------- last layer: fused aggregate + (64->1->1), unroll-8 ----------------

__global__ __launch_bounds__(256) void k_lastagg(const u16* __restrict__ hb,
                                                 const int* __restrict__ offs,
                                                 const int* __restrict__ ssrc,
                                                 const float* __restrict__ W1l,
                                                 const float* __restrict__ b1l,
                                                 const float* __restrict__ W2l,
                                                 const float* __restrict__ b2l,
                                                 float* __restrict__ o) {
    int w = threadIdx.x >> 6;
    int lane = threadIdx.x & 63;
    int half = lane >> 5;
    int li = lane & 31;
    int node = blockIdx.x * 8 + w * 2 + half;
    if (node >= N_NODES) return;
    const u32* hb32 = (const u32*)hb;
    float2 p = up2(hb32[node * 32 + li]);
    float v0 = p.x, v1 = p.y;
    int s = offs[node];
    int e = (node + 1 < N_NODES) ? offs[node + 1] : N_EDGES;
    int j = s;
    for (; j + 7 < e; j += 8) {
        int s0 = ssrc[j], s1 = ssrc[j + 1], s2 = ssrc[j + 2], s3 = ssrc[j + 3];
        int s4 = ssrc[j + 4], s5 = ssrc[j + 5], s6 = ssrc[j + 6], s7 = ssrc[j + 7];
        u32 n0 = hb32[s0 * 32 + li];
        u32 n1 = hb32[s1 * 32 + li];
        u32 n2 = hb32[s2 * 32 + li];
        u32 n3 = hb32[s3 * 32 + li];
        u32 n4 = hb32[s4 * 32 + li];
        u32 n5 = hb32[s5 * 32 + li];
        u32 n6 = hb32[s6 * 32 + li];
        u32 n7 = hb32[s7 * 32 + li];
        float2 a0 = up2(n0), a1 = up2(n1), a2 = up2(n2), a3 = up2(n3);
        float2 a4 = up2(n4), a5 = up2(n5), a6 = up2(n6), a7 = up2(n7);
        v0 += a0.x + a1.x + a2.x + a3.x + a4.x + a5.x + a6.x + a7.x;
        v1 += a0.y + a1.y + a2.y + a3.y + a4.y + a5.y + a6.y + a7.y;
    }
    if (j + 3 < e) {
        int s0 = ssrc[j], s1 = ssrc[j + 1], s2 = ssrc[j + 2], s3 = ssrc[j + 3];
        u32 n0 = hb32[s0 * 32 + li];
        u32 n1 = hb32[s1 * 32 + li];
        u32 n2 = hb32[s2 * 32 + li];
        u32 n3 = hb32[s3 * 32 + li];
        float2 a0 = up2(n0), a1 = up2(n1), a2 = up2(n2), a3 = up2(n3);
        v0 += a0.x + a1.x + a2.x + a3.x;
        v1 += a0.y + a1.y + a2.y + a3.y;
        j += 4;
    }
    for (; j < e; ++j) {
        float2 a = up2(hb32[ssrc[j] * 32 + li]);
        v0 += a.x; v1 += a.y;
    }
    float v = v0 * W1l[2 * li] + v1 * W1l[2 * li + 1];
#pragma unroll
    for (int off = 16; off; off >>= 1) v += __shfl_xor(v, off);  // within 32-lane half
    if (li == 0) {
        float h1 = fmaxf(v + b1l[0], 0.0f);
        o[node] = fmaf(h1, W2l[0], b2l[0]);
    }
}

// ---------------- mean pool ----------------

__global__ __launch_bounds__(256) void k_pool(const float* __restrict__ o,
                                              const int* __restrict__ batch,
                                              float* __restrict__ out) {
    int g = blockIdx.x;
    int lo = 0, hi = N_NODES;
    while (lo < hi) { int mid = (lo + hi) >> 1; if (batch[mid] < g) lo = mid + 1; else hi = mid; }
    int start = lo;
    hi = N_NODES;
    while (lo < hi) { int mid = (lo + hi) >> 1; if (batch[mid] < g + 1) lo = mid + 1; else hi = mid; }
    int end = lo;

    float s = 0.0f;
    for (int i = start + threadIdx.x; i < end; i += 256) s += o[i];
#pragma unroll
    for (int off = 32; off; off >>= 1) s += __shfl_xor(s, off);
    __shared__ float red[4];
    int lane = threadIdx.x & 63, wid = threadIdx.x >> 6;
    if (lane == 0) red[wid] = s;
    __syncthreads();
    if (threadIdx.x == 0) {
        float t = red[0] + red[1] + red[2] + red[3];
        float c = (float)(end - start);
        out[g] = t / fmaxf(c, 1.0f);
    }
}

// ---------------- launch ----------------

extern "C" void kernel_launch(void* const* d_in, const int* in_sizes, int n_in,
                              void* d_out, int out_size, void* d_ws, size_t ws_size,
                              hipStream_t stream) {
    const float* x    = (const float*)d_in[0];
    const int*   ei   = (const int*)d_in[1];   // [2][N_EDGES]
    const int*   bat  = (const int*)d_in[2];
    const float* W1   = (const float*)d_in[3];
    const float* b1   = (const float*)d_in[4];
    const float* W2   = (const float*)d_in[5];
    const float* b2   = (const float*)d_in[6];
    const float* W1l  = (const float*)d_in[7];
    const float* b1l  = (const float*)d_in[8];
    const float* W2l  = (const float*)d_in[9];
    const float* b2l  = (const float*)d_in[10];
    float* out = (float*)d_out;

    const int* srcI = ei;            // row 0
    const int* dstI = ei + N_EDGES;  // row 1

    // workspace carve-up (all 16B-aligned)
    char* ws = (char*)d_ws;
    u32*   aggb  = (u32*)ws;                                ws += (size_t)N_NODES * 32 * 4;
    u16*   hb    = (u16*)ws;                                ws += (size_t)N_NODES * FEAT * 2;
    int*   offs  = (int*)ws;                                ws += (size_t)N_NODES * 4;
    int*   ssrc  = (int*)ws;                                ws += (size_t)N_EDGES * 4;
    int*   tmp   = (int*)ws;                                ws += (size_t)NCB * CB_CAP * 4;
    float* onode = (float*)ws;                              ws += (size_t)N_NODES * 4;
    int*   bsum  = (int*)ws;                                ws += 128 * 4;
    int*   bhist = (int*)ws;                                ws += (size_t)NCB * PB * 4;
    int*   gtot  = (int*)ws;                                ws += ((NCB + 3) & ~3) * 4;

    k_phist<<<PB, 256, 0, stream>>>(dstI, bhist);
    k_pscan<<<NCB, PB, 0, stream>>>(bhist, gtot);
    k_pscatter<<<PB, 256, 0, stream>>>(srcI, dstI, bhist, tmp);
    k_bdeg<<<NCB, 256, 0, stream>>>(tmp, gtot, offs);
    k_scan1<<<SCAN_BLOCKS, 256, 0, stream>>>(offs, bsum);
    k_scan2<<<1, 128, 0, stream>>>(bsum);
    k_scan3<<<SCAN_BLOCKS, 256, 0, stream>>>(offs, bsum);
    k_bsort<<<NCB, 256, 0, stream>>>(tmp, offs, gtot, ssrc);
    k_cvt<<<(N_NODES * FEAT / 8 + 255) / 256, 256, 0, stream>>>(x, hb);

    const int ngrid = (N_NODES + 7) / 8;      // aggregate: 8 nodes (2 per wave) per block

    for (int l = 0; l < 4; ++l) {
        k_aggregate<<<ngrid, 256, 0, stream>>>(hb, aggb, offs, ssrc);
        k_mlp<<<MLP_BLOCKS, 256, 0, stream>>>(aggb, (u32*)hb,
                                              W1 + (size_t)l * FEAT * FEAT,
                                              b1 + (size_t)l * FEAT,
                                              W2 + (size_t)l * FEAT * FEAT,
                                              b2 + (size_t)l * FEAT);
    }
    k_lastagg<<<ngrid, 256, 0, stream>>>(hb, offs, ssrc, W1l, b1l, W2l, b2l, onode);
    k_pool<<<NGRAPH, 256, 0, stream>>>(onode, bat, out);
}

// Round 12
// 306.794 us; speedup vs baseline: 2.2344x; 1.0529x over previous
//
#include <hip/hip_runtime.h>
#include <hip/hip_bf16.h>

#define N_NODES 100000
#define N_EDGES 1600000
#define FEAT 64
#define NGRAPH 256

#define SCAN_CHUNK 1024
#define SCAN_BLOCKS ((N_NODES + SCAN_CHUNK - 1) / SCAN_CHUNK)  // 98

// coarse buckets: 1024 nodes each
#define CB_SHIFT 10
#define CB_NODES 1024
#define NCB ((N_NODES + CB_NODES - 1) / CB_NODES)   // 98
#define CB_CAP 18432                                 // slots per bucket

#define PB 512                                       // partition blocks
#define EPB ((N_EDGES + PB - 1) / PB)                // 3125 edges per block

#define NTILES (N_NODES / 16)                        // 6250 (exact)
#define MLP_BLOCKS 1024

typedef unsigned short u16;
typedef unsigned int u32;
typedef __attribute__((ext_vector_type(8))) short short8;
typedef __attribute__((ext_vector_type(4))) float f32x4;

static __device__ __forceinline__ float bf2f(u16 h) {
    return __uint_as_float(((u32)h) << 16);
}
static __device__ __forceinline__ u16 f2bf(float x) {  // round-to-nearest-even (finite)
    u32 u = __float_as_uint(x);
    return (u16)((u + 0x7FFF + ((u >> 16) & 1)) >> 16);
}
static __device__ __forceinline__ float2 up2(u32 v) {
    return make_float2(bf2f((u16)(v & 0xFFFF)), bf2f((u16)(v >> 16)));
}
static __device__ __forceinline__ short8 as_short8(uint4 v) {
    union { uint4 u; short8 s; } c; c.u = v; return c.s;
}

// ---------------- two-pass multisplit partition into coarse buckets ----------------

__global__ __launch_bounds__(256) void k_phist(const int* __restrict__ dst,
                                               int* __restrict__ bhist) {
    __shared__ int cnt[NCB];
    int t = threadIdx.x;
    for (int i = t; i < NCB; i += 256) cnt[i] = 0;
    __syncthreads();
    int begin = blockIdx.x * EPB;
    int end = begin + EPB; if (end > N_EDGES) end = N_EDGES;
    for (int e = begin + t; e < end; e += 256)
        atomicAdd(&cnt[dst[e] >> CB_SHIFT], 1);
    __syncthreads();
    for (int i = t; i < NCB; i += 256) bhist[i * PB + blockIdx.x] = cnt[i];
}

__global__ __launch_bounds__(PB) void k_pscan(int* __restrict__ bhist,
                                              int* __restrict__ gtot) {
    __shared__ int s[PB];
    int b = blockIdx.x, t = threadIdx.x;
    int v = bhist[b * PB + t];
    s[t] = v;
    __syncthreads();
    for (int off = 1; off < PB; off <<= 1) {
        int add = (t >= off) ? s[t - off] : 0;
        __syncthreads();
        s[t] += add;
        __syncthreads();
    }
    int incl = s[t];
    bhist[b * PB + t] = (t ? s[t - 1] : 0);
    if (t == PB - 1) gtot[b] = incl;
}

__global__ __launch_bounds__(256) void k_pscatter(const int* __restrict__ src,
                                                  const int* __restrict__ dst,
                                                  const int* __restrict__ bhist,
                                                  int* __restrict__ tmp) {
    __shared__ int cur[NCB];
    int t = threadIdx.x;
    for (int i = t; i < NCB; i += 256) cur[i] = bhist[i * PB + blockIdx.x];
    __syncthreads();
    int begin = blockIdx.x * EPB;
    int end = begin + EPB; if (end > N_EDGES) end = N_EDGES;
    for (int e = begin + t; e < end; e += 256) {
        int d = dst[e];
        int b = d >> CB_SHIFT;
        int pos = atomicAdd(&cur[b], 1);
        if (pos < CB_CAP) tmp[b * CB_CAP + pos] = ((d & (CB_NODES - 1)) << 17) | src[e];
    }
}

// ---------------- per-bucket degree count ----------------

__global__ __launch_bounds__(256) void k_bdeg(const int* __restrict__ tmp,
                                              const int* __restrict__ gtot,
                                              int* __restrict__ deg) {
    __shared__ int cnt[CB_NODES];
    int b = blockIdx.x, t = threadIdx.x;
    for (int j = t; j < CB_NODES; j += 256) cnt[j] = 0;
    __syncthreads();
    int n = gtot[b]; if (n > CB_CAP) n = CB_CAP;
    const int* tp = &tmp[b * CB_CAP];
    for (int i = t; i < n; i += 256) atomicAdd(&cnt[tp[i] >> 17], 1);
    __syncthreads();
    int n0 = b << CB_SHIFT;
    for (int j = t; j < CB_NODES; j += 256) {
        int node = n0 + j;
        if (node < N_NODES) deg[node] = cnt[j];
    }
}

// ---------------- CSR offset scan ----------------

__global__ __launch_bounds__(256) void k_scan1(const int* __restrict__ deg,
                                               int* __restrict__ bsum) {
    int t = threadIdx.x;
    int base = blockIdx.x * SCAN_CHUNK + t * 4;
    int4 d = make_int4(0, 0, 0, 0);
    if (base + 3 < N_NODES) {
        d = *reinterpret_cast<const int4*>(&deg[base]);
    } else {
        if (base + 0 < N_NODES) d.x = deg[base + 0];
        if (base + 1 < N_NODES) d.y = deg[base + 1];
        if (base + 2 < N_NODES) d.z = deg[base + 2];
    }
    int v = d.x + d.y + d.z + d.w;
#pragma unroll
    for (int off = 32; off; off >>= 1) v += __shfl_xor(v, off);
    __shared__ int red[4];
    int lane = t & 63, wid = t >> 6;
    if (lane == 0) red[wid] = v;
    __syncthreads();
    if (t == 0) bsum[blockIdx.x] = red[0] + red[1] + red[2] + red[3];
}

__global__ __launch_bounds__(128) void k_scan2(int* __restrict__ bsum) {
    __shared__ int s[128];
    int t = threadIdx.x;
    int v = (t < SCAN_BLOCKS) ? bsum[t] : 0;
    s[t] = v;
    __syncthreads();
    for (int off = 1; off < 128; off <<= 1) {
        int add = (t >= off) ? s[t - off] : 0;
        __syncthreads();
        s[t] += add;
        __syncthreads();
    }
    if (t < SCAN_BLOCKS) bsum[t] = (t ? s[t - 1] : 0);
}

__global__ __launch_bounds__(256) void k_scan3(int* __restrict__ deg_off,
                                               const int* __restrict__ bsum) {
    int t = threadIdx.x;
    int base = blockIdx.x * SCAN_CHUNK + t * 4;
    int4 d = make_int4(0, 0, 0, 0);
    bool full = (base + 3 < N_NODES);
    if (full) {
        d = *reinterpret_cast<const int4*>(&deg_off[base]);
    } else {
        if (base + 0 < N_NODES) d.x = deg_off[base + 0];
        if (base + 1 < N_NODES) d.y = deg_off[base + 1];
        if (base + 2 < N_NODES) d.z = deg_off[base + 2];
    }
    int total = d.x + d.y + d.z + d.w;
    __shared__ int sc[256];
    sc[t] = total;
    __syncthreads();
    for (int off = 1; off < 256; off <<= 1) {
        int add = (t >= off) ? sc[t - off] : 0;
        __syncthreads();
        sc[t] += add;
        __syncthreads();
    }
    int texc = (t ? sc[t - 1] : 0) + bsum[blockIdx.x];
    int4 o;
    o.x = texc;
    o.y = o.x + d.x;
    o.z = o.y + d.y;
    o.w = o.z + d.z;
    if (full) {
        *reinterpret_cast<int4*>(&deg_off[base]) = o;
    } else {
        if (base + 0 < N_NODES) deg_off[base + 0] = o.x;
        if (base + 1 < N_NODES) deg_off[base + 1] = o.y;
        if (base + 2 < N_NODES) deg_off[base + 2] = o.z;
    }
}

// ---------------- per-bucket scatter into CSR order ----------------

__global__ __launch_bounds__(256) void k_bsort(const int* __restrict__ tmp,
                                               const int* __restrict__ offs,
                                               const int* __restrict__ gtot,
                                               int* __restrict__ ssrc) {
    __shared__ int lcur[CB_NODES];
    int b = blockIdx.x;
    int n0 = b << CB_SHIFT;
    int t = threadIdx.x;
    for (int j = t; j < CB_NODES; j += 256) {
        int n = n0 + j;
        lcur[j] = (n < N_NODES) ? offs[n] : 0;
    }
    __syncthreads();
    int cnt = gtot[b]; if (cnt > CB_CAP) cnt = CB_CAP;
    const int* tp = &tmp[b * CB_CAP];
    for (int i = t; i < cnt; i += 256) {
        int p = tp[i];
        int pos = atomicAdd(&lcur[p >> 17], 1);
        ssrc[pos] = p & 0x1FFFF;
    }
}

// ---------------- x (f32) -> bf16 node table ----------------

__global__ __launch_bounds__(256) void k_cvt(const float* __restrict__ x,
                                             u16* __restrict__ hb) {
    int i = blockIdx.x * 256 + threadIdx.x;  // 8 elems each
    const int total = N_NODES * FEAT / 8;
    if (i < total) {
        const float4* xv = (const float4*)x;
        float4 a = xv[2 * i], b = xv[2 * i + 1];
        uint4 o;
        o.x = f2bf(a.x) | ((u32)f2bf(a.y) << 16);
        o.y = f2bf(a.z) | ((u32)f2bf(a.w) << 16);
        o.z = f2bf(b.x) | ((u32)f2bf(b.y) << 16);
        o.w = f2bf(b.z) | ((u32)f2bf(b.w) << 16);
        ((uint4*)hb)[i] = o;
    }
}

// ---------------- GIN aggregation: 4 nodes/wave (16-lane groups), 8B/lane, unroll-8 ----------------
// Lane group g owns one node; lane reads uint2 (4 feats). One VMEM instr covers 4 rows (512B).

__global__ __launch_bounds__(256) void k_aggregate(const u16* __restrict__ hb,
                                                   u32* __restrict__ aggb,
                                                   const int* __restrict__ offs,
                                                   const int* __restrict__ ssrc) {
    int grp = threadIdx.x >> 4;        // 16 node-groups per block
    int li = threadIdx.x & 15;
    int node = blockIdx.x * 16 + grp;
    if (node >= N_NODES) return;
    const uint2* hb2 = (const uint2*)hb;
    uint2 pv = hb2[(size_t)node * 16 + li];
    float2 pa = up2(pv.x), pb = up2(pv.y);
    float v0 = pa.x, v1 = pa.y, v2 = pb.x, v3 = pb.y;
    int s = offs[node];
    int e = (node + 1 < N_NODES) ? offs[node + 1] : N_EDGES;
    int j = s;
    for (; j + 7 < e; j += 8) {
        int s0 = ssrc[j], s1 = ssrc[j + 1], s2 = ssrc[j + 2], s3 = ssrc[j + 3];
        int s4 = ssrc[j + 4], s5 = ssrc[j + 5], s6 = ssrc[j + 6], s7 = ssrc[j + 7];
        uint2 n0 = hb2[(size_t)s0 * 16 + li];
        uint2 n1 = hb2[(size_t)s1 * 16 + li];
        uint2 n2 = hb2[(size_t)s2 * 16 + li];
        uint2 n3 = hb2[(size_t)s3 * 16 + li];
        uint2 n4 = hb2[(size_t)s4 * 16 + li];
        uint2 n5 = hb2[(size_t)s5 * 16 + li];
        uint2 n6 = hb2[(size_t)s6 * 16 + li];
        uint2 n7 = hb2[(size_t)s7 * 16 + li];
        float2 a0 = up2(n0.x), b0 = up2(n0.y), a1 = up2(n1.x), b1 = up2(n1.y);
        float2 a2 = up2(n2.x), b2 = up2(n2.y), a3 = up2(n3.x), b3 = up2(n3.y);
        float2 a4 = up2(n4.x), b4 = up2(n4.y), a5 = up2(n5.x), b5 = up2(n5.y);
        float2 a6 = up2(n6.x), b6 = up2(n6.y), a7 = up2(n7.x), b7 = up2(n7.y);
        v0 += a0.x + a1.x + a2.x + a3.x + a4.x + a5.x + a6.x + a7.x;
        v1 += a0.y + a1.y + a2.y + a3.y + a4.y + a5.y + a6.y + a7.y;
        v2 += b0.x + b1.x + b2.x + b3.x + b4.x + b5.x + b6.x + b7.x;
        v3 += b0.y + b1.y + b2.y + b3.y + b4.y + b5.y + b6.y + b7.y;
    }
    if (j + 3 < e) {
        int s0 = ssrc[j], s1 = ssrc[j + 1], s2 = ssrc[j + 2], s3 = ssrc[j + 3];
        uint2 n0 = hb2[(size_t)s0 * 16 + li];
        uint2 n1 = hb2[(size_t)s1 * 16 + li];
        uint2 n2 = hb2[(size_t)s2 * 16 + li];
        uint2 n3 = hb2[(size_t)s3 * 16 + li];
        float2 a0 = up2(n0.x), b0 = up2(n0.y), a1 = up2(n1.x), b1 = up2(n1.y);
        float2 a2 = up2(n2.x), b2 = up2(n2.y), a3 = up2(n3.x), b3 = up2(n3.y);
        v0 += a0.x + a1.x + a2.x + a3.x;
        v1 += a0.y + a1.y + a2.y + a3.y;
        v2 += b0.x + b1.x + b2.x + b3.x;
        v3 += b0.y + b1.y + b2.y + b3.y;
        j += 4;
    }
    for (; j < e; ++j) {
        uint2 nv = hb2[(size_t)ssrc[j] * 16 + li];
        float2 a = up2(nv.x), b = up2(nv.y);
        v0 += a.x; v1 += a.y; v2 += b.x; v3 += b.y;
    }
    uint2 o;
    o.x = f2bf(v0) | ((u32)f2bf(v1) << 16);
    o.y = f2bf(v2) | ((u32)f2bf(v3) << 16);
    ((uint2*)aggb)[(size_t)node * 16 + li] = o;
}

// ---------------- MFMA fused 64->64->64 MLP (verified R10) ----------------

__global__ __launch_bounds__(256) void k_mlp(const u32* __restrict__ aggb,
                                             u32* __restrict__ hout32,
                                             const float* __restrict__ W1,
                                             const float* __restrict__ b1,
                                             const float* __restrict__ W2,
                                             const float* __restrict__ b2) {
    __shared__ __align__(16) u32 lds[4 * 2 * 576];  // per wave: H[16][36] + O[16][36] u32
    int wid = threadIdx.x >> 6;
    int lane = threadIdx.x & 63;
    int m = lane & 15;   // node-in-tile (D col / B-frag N)
    int g = lane >> 4;   // lane group
    u32* H = &lds[wid * 2 * 576];
    u32* O = H + 576;

    // Weights as A-fragments (W^T), biases for D rows — loaded once per wave.
    short8 A1[4][2], A2[4][2];
    float bv1[4][4], bv2[4][4];
#pragma unroll
    for (int nt = 0; nt < 4; ++nt) {
        int n = nt * 16 + m;
#pragma unroll
        for (int kh = 0; kh < 2; ++kh) {
            short8 s1, s2;
#pragma unroll
            for (int j = 0; j < 8; ++j) {
                int k = kh * 32 + g * 8 + j;
                s1[j] = (short)f2bf(W1[k * 64 + n]);
                s2[j] = (short)f2bf(W2[k * 64 + n]);
            }
            A1[nt][kh] = s1;
            A2[nt][kh] = s2;
        }
#pragma unroll
        for (int r = 0; r < 4; ++r) {
            bv1[nt][r] = b1[nt * 16 + g * 4 + r];
            bv2[nt][r] = b2[nt * 16 + g * 4 + r];
        }
    }

    int gwave = blockIdx.x * 4 + wid;
    int nwaves = gridDim.x * 4;
    for (int tile = gwave; tile < NTILES; tile += nwaves) {
        int nodeBase = tile * 16;
        const uint4* bp = (const uint4*)(aggb + (size_t)(nodeBase + m) * 32);
        short8 B0 = as_short8(bp[g]);        // kh=0
        short8 B1f = as_short8(bp[4 + g]);   // kh=1

#pragma unroll
        for (int nt = 0; nt < 4; ++nt) {
            f32x4 acc = { bv1[nt][0], bv1[nt][1], bv1[nt][2], bv1[nt][3] };
            acc = __builtin_amdgcn_mfma_f32_16x16x32_bf16(A1[nt][0], B0, acc, 0, 0, 0);
            acc = __builtin_amdgcn_mfma_f32_16x16x32_bf16(A1[nt][1], B1f, acc, 0, 0, 0);
            float h0 = fmaxf(acc[0], 0.0f), h1 = fmaxf(acc[1], 0.0f);
            float h2 = fmaxf(acc[2], 0.0f), h3 = fmaxf(acc[3], 0.0f);
            H[m * 36 + nt * 8 + g * 2 + 0] = f2bf(h0) | ((u32)f2bf(h1) << 16);
            H[m * 36 + nt * 8 + g * 2 + 1] = f2bf(h2) | ((u32)f2bf(h3) << 16);
        }
        const uint4* hp = (const uint4*)H;
        short8 HB0 = as_short8(hp[9 * m + g]);
        short8 HB1 = as_short8(hp[9 * m + g + 4]);

#pragma unroll
        for (int nt = 0; nt < 4; ++nt) {
            f32x4 acc = { bv2[nt][0], bv2[nt][1], bv2[nt][2], bv2[nt][3] };
            acc = __builtin_amdgcn_mfma_f32_16x16x32_bf16(A2[nt][0], HB0, acc, 0, 0, 0);
            acc = __builtin_amdgcn_mfma_f32_16x16x32_bf16(A2[nt][1], HB1, acc, 0, 0, 0);
            float o0 = fmaxf(acc[0], 0.0f), o1 = fmaxf(acc[1], 0.0f);
            float o2 = fmaxf(acc[2], 0.0f), o3 = fmaxf(acc[3], 0.0f);
            O[m * 36 + nt * 8 + g * 2 + 0] = f2bf(o0) | ((u32)f2bf(o1) << 16);
            O[m * 36 + nt * 8 + g * 2 + 1] = f2bf(o2) | ((u32)f2bf(o3) << 16);
        }
        int m2 = lane >> 2;
        int q = (lane & 3) * 8;
        const uint4* op = (const uint4*)O;
        uint4 w0 = op[(m2 * 36 + q) >> 2];
        uint4 w1 = op[(m2 * 36 + q + 4) >> 2];
        uint4* gp = (uint4*)(hout32 + (size_t)(nodeBase + m2) * 32 + q);
        gp[0] = w0;
        gp[1] = w1;
    }
}

// ---------------- last layer: fused aggregate + (64->1->1), 4 nodes/wave ----------------

__global__ __launch_bounds__(256) void k_lastagg(const u16* __restrict__ hb,
                                                 const int* __restrict__ offs,
                                                 const int* __restrict__ ssrc,
                                                 const float* __restrict__ W1l,
                                                 const float* __restrict__ b1l,
                                                 const float* __restrict__ W2l,
                                                 const float* __restrict__ b2l,
                                                 float* __restrict__ o) {
    int grp = threadIdx.x >> 4;
    int li = threadIdx.x & 15;
    int node = blockIdx.x * 16 + grp;
    if (node >= N_NODES) return;
    const uint2* hb2 = (const uint2*)hb;
    uint2 pv = hb2[(size_t)node * 16 + li];
    float2 pa = up2(pv.x), pb = up2(pv.y);
    float v0 = pa.x, v1 = pa.y, v2 = pb.x, v3 = pb.y;
    int s = offs[node];
    int e = (node + 1 < N_NODES) ? offs[node + 1] : N_EDGES;
    int j = s;
    for (; j + 7 < e; j += 8) {
        int s0 = ssrc[j], s1 = ssrc[j + 1], s2 = ssrc[j + 2], s3 = ssrc[j + 3];
        int s4 = ssrc[j + 4], s5 = ssrc[j + 5], s6 = ssrc[j + 6], s7 = ssrc[j + 7];
        uint2 n0 = hb2[(size_t)s0 * 16 + li];
        uint2 n1 = hb2[(size_t)s1 * 16 + li];
        uint2 n2 = hb2[(size_t)s2 * 16 + li];
        uint2 n3 = hb2[(size_t)s3 * 16 + li];
        uint2 n4 = hb2[(size_t)s4 * 16 + li];
        uint2 n5 = hb2[(size_t)s5 * 16 + li];
        uint2 n6 = hb2[(size_t)s6 * 16 + li];
        uint2 n7 = hb2[(size_t)s7 * 16 + li];
        float2 a0 = up2(n0.x), b0 = up2(n0.y), a1 = up2(n1.x), b1 = up2(n1.y);
        float2 a2 = up2(n2.x), b2 = up2(n2.y), a3 = up2(n3.x), b3 = up2(n3.y);
        float2 a4 = up2(n4.x), b4 = up2(n4.y), a5 = up2(n5.x), b5 = up2(n5.y);
        float2 a6 = up2(n6.x), b6 = up2(n6.y), a7 = up2(n7.x), b7 = up2(n7.y);
        v0 += a0.x + a1.x + a2.x + a3.x + a4.x + a5.x + a6.x + a7.x;
        v1 += a0.y + a1.y + a2.y + a3.y + a4.y + a5.y + a6.y + a7.y;
        v2 += b0.x + b1.x + b2.x + b3.x + b4.x + b5.x + b6.x + b7.x;
        v3 += b0.y + b1.y + b2.y + b3.y + b4.y + b5.y + b6.y + b7.y;
    }
    if (j + 3 < e) {
        int s0 = ssrc[j], s1 = ssrc[j + 1], s2 = ssrc[j + 2], s3 = ssrc[j + 3];
        uint2 n0 = hb2[(size_t)s0 * 16 + li];
        uint2 n1 = hb2[(size_t)s1 * 16 + li];
        uint2 n2 = hb2[(size_t)s2 * 16 + li];
        uint2 n3 = hb2[(size_t)s3 * 16 + li];
        float2 a0 = up2(n0.x), b0 = up2(n0.y), a1 = up2(n1.x), b1 = up2(n1.y);
        float2 a2 = up2(n2.x), b2 = up2(n2.y), a3 = up2(n3.x), b3 = up2(n3.y);
        v0 += a0.x + a1.x + a2.x + a3.x;
        v1 += a0.y + a1.y + a2.y + a3.y;
        v2 += b0.x + b1.x + b2.x + b3.x;
        v3 += b0.y + b1.y + b2.y + b3.y;
        j += 4;
    }
    for (; j < e; ++j) {
        uint2 nv = hb2[(size_t)ssrc[j] * 16 + li];
        float2 a = up2(nv.x), b = up2(nv.y);
        v0 += a.x; v1 += a.y; v2 += b.x; v3 += b.y;
    }
    float4 wv = ((const float4*)W1l)[li];
    float v = v0 * wv.x + v1 * wv.y + v2 * wv.z + v3 * wv.w;
#pragma unroll
    for (int off = 8; off; off >>= 1) v += __shfl_xor(v, off);  // within 16-lane group
    if (li == 0) {
        float h1 = fmaxf(v + b1l[0], 0.0f);
        o[node] = fmaf(h1, W2l[0], b2l[0]);
    }
}

// ---------------- mean pool ----------------

__global__ __launch_bounds__(256) void k_pool(const float* __restrict__ o,
                                              const int* __restrict__ batch,
                                              float* __restrict__ out) {
    int g = blockIdx.x;
    int lo = 0, hi = N_NODES;
    while (lo < hi) { int mid = (lo + hi) >> 1; if (batch[mid] < g) lo = mid + 1; else hi = mid; }
    int start = lo;
    hi = N_NODES;
    while (lo < hi) { int mid = (lo + hi) >> 1; if (batch[mid] < g + 1) lo = mid + 1; else hi = mid; }
    int end = lo;

    float s = 0.0f;
    for (int i = start + threadIdx.x; i < end; i += 256) s += o[i];
#pragma unroll
    for (int off = 32; off; off >>= 1) s += __shfl_xor(s, off);
    __shared__ float red[4];
    int lane = threadIdx.x & 63, wid = threadIdx.x >> 6;
    if (lane == 0) red[wid] = s;
    __syncthreads();
    if (threadIdx.x == 0) {
        float t = red[0] + red[1] + red[2] + red[3];
        float c = (float)(end - start);
        out[g] = t / fmaxf(c, 1.0f);
    }
}

// ---------------- launch ----------------

extern "C" void kernel_launch(void* const* d_in, const int* in_sizes, int n_in,
                              void* d_out, int out_size, void* d_ws, size_t ws_size,
                              hipStream_t stream) {
    const float* x    = (const float*)d_in[0];
    const int*   ei   = (const int*)d_in[1];   // [2][N_EDGES]
    const int*   bat  = (const int*)d_in[2];
    const float* W1   = (const float*)d_in[3];
    const float* b1   = (const float*)d_in[4];
    const float* W2   = (const float*)d_in[5];
    const float* b2   = (const float*)d_in[6];
    const float* W1l  = (const float*)d_in[7];
    const float* b1l  = (const float*)d_in[8];
    const float* W2l  = (const float*)d_in[9];
    const float* b2l  = (const float*)d_in[10];
    float* out = (float*)d_out;

    const int* srcI = ei;            // row 0
    const int* dstI = ei + N_EDGES;  // row 1

    // workspace carve-up (all 16B-aligned)
    char* ws = (char*)d_ws;
    u32*   aggb  = (u32*)ws;                                ws += (size_t)N_NODES * 32 * 4;
    u16*   hb    = (u16*)ws;                                ws += (size_t)N_NODES * FEAT * 2;
    int*   offs  = (int*)ws;                                ws += (size_t)N_NODES * 4;
    int*   ssrc  = (int*)ws;                                ws += (size_t)N_EDGES * 4;
    int*   tmp   = (int*)ws;                                ws += (size_t)NCB * CB_CAP * 4;
    float* onode = (float*)ws;                              ws += (size_t)N_NODES * 4;
    int*   bsum  = (int*)ws;                                ws += 128 * 4;
    int*   bhist = (int*)ws;                                ws += (size_t)NCB * PB * 4;
    int*   gtot  = (int*)ws;                                ws += ((NCB + 3) & ~3) * 4;

    k_phist<<<PB, 256, 0, stream>>>(dstI, bhist);
    k_pscan<<<NCB, PB, 0, stream>>>(bhist, gtot);
    k_pscatter<<<PB, 256, 0, stream>>>(srcI, dstI, bhist, tmp);
    k_bdeg<<<NCB, 256, 0, stream>>>(tmp, gtot, offs);
    k_scan1<<<SCAN_BLOCKS, 256, 0, stream>>>(offs, bsum);
    k_scan2<<<1, 128, 0, stream>>>(bsum);
    k_scan3<<<SCAN_BLOCKS, 256, 0, stream>>>(offs, bsum);
    k_bsort<<<NCB, 256, 0, stream>>>(tmp, offs, gtot, ssrc);
    k_cvt<<<(N_NODES * FEAT / 8 + 255) / 256, 256, 0, stream>>>(x, hb);

    const int ngrid = (N_NODES + 15) / 16;    // gather: 16 node-groups per block

    for (int l = 0; l < 4; ++l) {
        k_aggregate<<<ngrid, 256, 0, stream>>>(hb, aggb, offs, ssrc);
        k_mlp<<<MLP_BLOCKS, 256, 0, stream>>>(aggb, (u32*)hb,
                                              W1 + (size_t)l * FEAT * FEAT,
                                              b1 + (size_t)l * FEAT,
                                              W2 + (size_t)l * FEAT * FEAT,
                                              b2 + (size_t)l * FEAT);
    }
    k_lastagg<<<ngrid, 256, 0, stream>>>(hb, offs, ssrc, W1l, b1l, W2l, b2l, onode);
    k_pool<<<NGRAPH, 256, 0, stream>>>(onode, bat, out);
}